// Round 1
// baseline (843.166 us; speedup 1.0000x reference)
//
#include <hip/hip_runtime.h>

// GCN 2-layer: N=100000 nodes, E=1600000 edges, 64 -> 64(relu) -> 33.
// out = [pos (N*32) | mass (N*1)], float32.
//
// Formulation: ht[i] = (x@W)[i] * dinv[i]
//   gcnconv(x)[i] = dinv[i] * ( sum_{e: dst=i} ht[src[e]] + ht[i] ) + b
// (per-edge norm = dinv[src]*dinv[dst] folds into ht and the dst-side scale)

constexpr int NN = 100000;
constexpr int NE = 1600000;
constexpr int D1 = 64;   // IN_DIM == HID
constexpr int D2 = 33;   // OUT + 1
constexpr int OUTD = 32;

// ---------------- degree / dinv ----------------

__global__ void k_deg(const int* __restrict__ dst, float* __restrict__ deg) {
    int e = blockIdx.x * blockDim.x + threadIdx.x;
    if (e < NE) atomicAdd(&deg[dst[e]], 1.0f);
}

__global__ void k_dinv(float* __restrict__ deg_dinv) {
    int i = blockIdx.x * blockDim.x + threadIdx.x;
    if (i < NN) deg_dinv[i] = rsqrtf(deg_dinv[i] + 1.0f);
}

// ---------------- layer 1 GEMM: ht = (x @ W1) * dinv, seed agg = ht ----------------

__global__ __launch_bounds__(256) void k_gemm1(const float* __restrict__ x,
                                               const float* __restrict__ W1,
                                               const float* __restrict__ dinv,
                                               float* __restrict__ ht,
                                               float* __restrict__ agg) {
    __shared__ float w[64 * 64];
    for (int t = threadIdx.x; t < 64 * 64; t += 256) w[t] = W1[t];
    __syncthreads();

    int i = blockIdx.x * 256 + threadIdx.x;
    if (i >= NN) return;

    float xr[64];
    const float4* xp = reinterpret_cast<const float4*>(x + (size_t)i * 64);
    #pragma unroll
    for (int q = 0; q < 16; ++q) {
        float4 v = xp[q];
        xr[4 * q + 0] = v.x; xr[4 * q + 1] = v.y;
        xr[4 * q + 2] = v.z; xr[4 * q + 3] = v.w;
    }

    float acc[64];
    #pragma unroll
    for (int f = 0; f < 64; ++f) acc[f] = 0.f;

    for (int k = 0; k < 64; ++k) {
        float xk = xr[k];
        const float4* wr = reinterpret_cast<const float4*>(w + k * 64);
        #pragma unroll
        for (int f4 = 0; f4 < 16; ++f4) {
            float4 wv = wr[f4];
            acc[4 * f4 + 0] += xk * wv.x;
            acc[4 * f4 + 1] += xk * wv.y;
            acc[4 * f4 + 2] += xk * wv.z;
            acc[4 * f4 + 3] += xk * wv.w;
        }
    }

    float di = dinv[i];
    float4* hp = reinterpret_cast<float4*>(ht + (size_t)i * 64);
    float4* ap = reinterpret_cast<float4*>(agg + (size_t)i * 64);
    #pragma unroll
    for (int f4 = 0; f4 < 16; ++f4) {
        float4 v;
        v.x = acc[4 * f4 + 0] * di; v.y = acc[4 * f4 + 1] * di;
        v.z = acc[4 * f4 + 2] * di; v.w = acc[4 * f4 + 3] * di;
        hp[f4] = v; ap[f4] = v;
    }
}

// ---------------- layer 1 scatter: agg[dst] += ht[src], lane = feature ----------------

__global__ void k_scatter1(const int* __restrict__ src, const int* __restrict__ dst,
                           const float* __restrict__ ht, float* __restrict__ agg) {
    int t = blockIdx.x * blockDim.x + threadIdx.x;   // E*64 = 102.4M < 2^31
    int e = t >> 6, f = t & 63;
    if (e < NE) {
        int s = src[e], d = dst[e];
        atomicAdd(&agg[(size_t)d * 64 + f], ht[(size_t)s * 64 + f]);
    }
}

// ---------------- layer 1 finalize: h = relu(dinv*agg + b1) ----------------

__global__ void k_fin1(const float* __restrict__ agg, const float* __restrict__ dinv,
                       const float* __restrict__ b1, float* __restrict__ h) {
    int t = blockIdx.x * blockDim.x + threadIdx.x;   // N*64 = 6.4M
    if (t >= NN * 64) return;
    int i = t >> 6, f = t & 63;
    float v = dinv[i] * agg[t] + b1[f];
    h[t] = fmaxf(v, 0.f);
}

// ---------------- layer 2 GEMM: ht2 = (h @ W2) * dinv, seed agg2 = ht2 ----------------

__global__ __launch_bounds__(256) void k_gemm2(const float* __restrict__ h,
                                               const float* __restrict__ W2,
                                               const float* __restrict__ dinv,
                                               float* __restrict__ ht2,
                                               float* __restrict__ agg2) {
    __shared__ float w[64 * 36];   // padded stride 36 for float4 alignment
    for (int t = threadIdx.x; t < 64 * 36; t += 256) {
        int k = t / 36, c = t - k * 36;
        w[t] = (c < D2) ? W2[k * D2 + c] : 0.f;
    }
    __syncthreads();

    int i = blockIdx.x * 256 + threadIdx.x;
    if (i >= NN) return;

    float xr[64];
    const float4* xp = reinterpret_cast<const float4*>(h + (size_t)i * 64);
    #pragma unroll
    for (int q = 0; q < 16; ++q) {
        float4 v = xp[q];
        xr[4 * q + 0] = v.x; xr[4 * q + 1] = v.y;
        xr[4 * q + 2] = v.z; xr[4 * q + 3] = v.w;
    }

    float acc[36];
    #pragma unroll
    for (int c = 0; c < 36; ++c) acc[c] = 0.f;

    for (int k = 0; k < 64; ++k) {
        float xk = xr[k];
        const float4* wr = reinterpret_cast<const float4*>(w + k * 36);
        #pragma unroll
        for (int c4 = 0; c4 < 9; ++c4) {
            float4 wv = wr[c4];
            acc[4 * c4 + 0] += xk * wv.x;
            acc[4 * c4 + 1] += xk * wv.y;
            acc[4 * c4 + 2] += xk * wv.z;
            acc[4 * c4 + 3] += xk * wv.w;
        }
    }

    float di = dinv[i];
    float* hp = ht2 + (size_t)i * D2;
    float* ap = agg2 + (size_t)i * D2;
    for (int c = 0; c < D2; ++c) {
        float v = acc[c] * di;
        hp[c] = v; ap[c] = v;
    }
}

// ---------------- layer 2 scatter ----------------

__global__ void k_scatter2a(const int* __restrict__ src, const int* __restrict__ dst,
                            const float* __restrict__ ht2, float* __restrict__ agg2) {
    int t = blockIdx.x * blockDim.x + threadIdx.x;   // E*32 = 51.2M
    int e = t >> 5, f = t & 31;
    if (e < NE) {
        int s = src[e], d = dst[e];
        atomicAdd(&agg2[(size_t)d * D2 + f], ht2[(size_t)s * D2 + f]);
    }
}

__global__ void k_scatter2b(const int* __restrict__ src, const int* __restrict__ dst,
                            const float* __restrict__ ht2, float* __restrict__ agg2) {
    int e = blockIdx.x * blockDim.x + threadIdx.x;
    if (e < NE) {
        int s = src[e], d = dst[e];
        atomicAdd(&agg2[(size_t)d * D2 + 32], ht2[(size_t)s * D2 + 32]);
    }
}

// ---------------- layer 2 finalize: pos + exp(mass) to d_out ----------------

__global__ void k_fin2(const float* __restrict__ agg2, const float* __restrict__ dinv,
                       const float* __restrict__ b2, float* __restrict__ out) {
    int t = blockIdx.x * blockDim.x + threadIdx.x;   // N*32 = 3.2M
    if (t >= NN * 32) return;
    int i = t >> 5, c = t & 31;
    float di = dinv[i];
    out[t] = di * agg2[(size_t)i * D2 + c] + b2[c];
    if (c == 0) {
        float m = di * agg2[(size_t)i * D2 + 32] + b2[32];
        out[(size_t)NN * 32 + i] = expf(m);
    }
}

extern "C" void kernel_launch(void* const* d_in, const int* in_sizes, int n_in,
                              void* d_out, int out_size, void* d_ws, size_t ws_size,
                              hipStream_t stream) {
    const float* x  = (const float*)d_in[0];
    const float* W1 = (const float*)d_in[1];
    const float* b1 = (const float*)d_in[2];
    const float* W2 = (const float*)d_in[3];
    const float* b2 = (const float*)d_in[4];
    const int*   ei = (const int*)d_in[5];
    const int* src = ei;
    const int* dst = ei + NE;
    float* out = (float*)d_out;

    // workspace layout (floats): dinv[N] | bufA[N*64] | bufB[N*64] | bufC[N*33]
    float* ws   = (float*)d_ws;
    float* dinv = ws;
    float* bufA = ws + NN;                       // ht1, then h (relu output)
    float* bufB = bufA + (size_t)NN * 64;        // agg1, then ht2 (N*33)
    float* bufC = bufB + (size_t)NN * 64;        // agg2 (N*33)

    // degree (zero first — ws is not re-poisoned between replays)
    hipMemsetAsync(dinv, 0, (size_t)NN * sizeof(float), stream);
    k_deg<<<(NE + 255) / 256, 256, 0, stream>>>(dst, dinv);
    k_dinv<<<(NN + 255) / 256, 256, 0, stream>>>(dinv);

    // layer 1
    k_gemm1<<<(NN + 255) / 256, 256, 0, stream>>>(x, W1, dinv, bufA, bufB);
    {
        long long tot = (long long)NE * 64;
        k_scatter1<<<(int)((tot + 255) / 256), 256, 0, stream>>>(src, dst, bufA, bufB);
    }
    k_fin1<<<(NN * 64 + 255) / 256, 256, 0, stream>>>(bufB, dinv, b1, bufA);

    // layer 2
    k_gemm2<<<(NN + 255) / 256, 256, 0, stream>>>(bufA, W2, dinv, bufB, bufC);
    {
        long long tot = (long long)NE * 32;
        k_scatter2a<<<(int)((tot + 255) / 256), 256, 0, stream>>>(src, dst, bufB, bufC);
    }
    k_scatter2b<<<(NE + 255) / 256, 256, 0, stream>>>(src, dst, bufB, bufC);
    k_fin2<<<(NN * 32 + 255) / 256, 256, 0, stream>>>(bufC, dinv, b2, out);
}

// Round 2
// 477.265 us; speedup vs baseline: 1.7667x; 1.7667x over previous
//
#include <hip/hip_runtime.h>

// GCN 2-layer: N=100000 nodes, E=1600000 edges, 64 -> 64(relu) -> 33.
// out = [pos (N*32) | mass (N*1)], float32.
//
// ht[i] = (x@W)[i] * dinv[i]
// gcnconv(x)[i] = dinv[i] * ( sum_{e: dst=i} ht[src[e]] + ht[i] ) + b
//
// R2: atomics -> on-device CSR (counting sort by dst) + per-node wave gather,
// with finalize (dinv-scale + bias + relu / exp epilogue) fused into gathers.

constexpr int NN = 100000;
constexpr int NE = 1600000;
constexpr int D2 = 33;   // OUT + 1

constexpr int SCAN_CHUNK = 1024;                       // 256 thr x 4 items
constexpr int NB = (NN + SCAN_CHUNK - 1) / SCAN_CHUNK; // 98 (<=128)

// ---------------- degree count (int) ----------------

__global__ void k_cnt(const int* __restrict__ dst, int* __restrict__ cnt) {
    int e = blockIdx.x * blockDim.x + threadIdx.x;
    if (e < NE) atomicAdd(&cnt[dst[e]], 1);
}

__global__ void k_dinv(const int* __restrict__ cnt, float* __restrict__ dinv) {
    int i = blockIdx.x * blockDim.x + threadIdx.x;
    if (i < NN) dinv[i] = rsqrtf((float)cnt[i] + 1.0f);
}

// ---------------- exclusive scan of cnt -> rs[0..NN] ----------------

__global__ void k_blocksum(const int* __restrict__ cnt, int* __restrict__ bsum) {
    __shared__ int sh[256];
    int base = blockIdx.x * SCAN_CHUNK + threadIdx.x * 4;
    int s = 0;
    #pragma unroll
    for (int k = 0; k < 4; ++k) { int i = base + k; if (i < NN) s += cnt[i]; }
    sh[threadIdx.x] = s; __syncthreads();
    for (int off = 128; off > 0; off >>= 1) {
        if (threadIdx.x < off) sh[threadIdx.x] += sh[threadIdx.x + off];
        __syncthreads();
    }
    if (threadIdx.x == 0) bsum[blockIdx.x] = sh[0];
}

__global__ void k_scanbsum(const int* __restrict__ bsum, int* __restrict__ boff) {
    __shared__ int sh[128];
    int t = threadIdx.x;
    int v = (t < NB) ? bsum[t] : 0;
    sh[t] = v; __syncthreads();
    for (int off = 1; off < 128; off <<= 1) {
        int add = (t >= off) ? sh[t - off] : 0;
        __syncthreads();
        sh[t] += add;
        __syncthreads();
    }
    if (t < NB) boff[t] = sh[t] - v;   // exclusive
}

__global__ void k_scanfinal(const int* __restrict__ cnt, const int* __restrict__ boff,
                            int* __restrict__ rs) {
    __shared__ int sh[256];
    int t = threadIdx.x;
    int base = blockIdx.x * SCAN_CHUNK + t * 4;
    int v[4]; int s = 0;
    #pragma unroll
    for (int k = 0; k < 4; ++k) { int i = base + k; v[k] = (i < NN) ? cnt[i] : 0; s += v[k]; }
    sh[t] = s; __syncthreads();
    for (int off = 1; off < 256; off <<= 1) {
        int add = (t >= off) ? sh[t - off] : 0;
        __syncthreads();
        sh[t] += add;
        __syncthreads();
    }
    int ex = sh[t] - s + boff[blockIdx.x];
    #pragma unroll
    for (int k = 0; k < 4; ++k) {
        int i = base + k;
        if (i < NN) { rs[i] = ex; ex += v[k]; if (i == NN - 1) rs[NN] = ex; }
    }
}

// ---------------- bin edges into CSR ----------------

__global__ void k_bin(const int* __restrict__ src, const int* __restrict__ dst,
                      const int* __restrict__ rs, int* __restrict__ cursor,
                      int* __restrict__ csr) {
    int e = blockIdx.x * blockDim.x + threadIdx.x;
    if (e < NE) {
        int d = dst[e];
        int p = atomicAdd(&cursor[d], 1);
        csr[rs[d] + p] = src[e];
    }
}

// ---------------- layer 1 GEMM: ht = (x @ W1) * dinv ----------------

__global__ __launch_bounds__(256) void k_gemm1(const float* __restrict__ x,
                                               const float* __restrict__ W1,
                                               const float* __restrict__ dinv,
                                               float* __restrict__ ht) {
    __shared__ float w[64 * 64];
    for (int t = threadIdx.x; t < 64 * 64; t += 256) w[t] = W1[t];
    __syncthreads();

    int i = blockIdx.x * 256 + threadIdx.x;
    if (i >= NN) return;

    float xr[64];
    const float4* xp = reinterpret_cast<const float4*>(x + (size_t)i * 64);
    #pragma unroll
    for (int q = 0; q < 16; ++q) {
        float4 v = xp[q];
        xr[4 * q + 0] = v.x; xr[4 * q + 1] = v.y;
        xr[4 * q + 2] = v.z; xr[4 * q + 3] = v.w;
    }

    float acc[64];
    #pragma unroll
    for (int f = 0; f < 64; ++f) acc[f] = 0.f;

    for (int k = 0; k < 64; ++k) {
        float xk = xr[k];
        const float4* wr = reinterpret_cast<const float4*>(w + k * 64);
        #pragma unroll
        for (int f4 = 0; f4 < 16; ++f4) {
            float4 wv = wr[f4];
            acc[4 * f4 + 0] += xk * wv.x;
            acc[4 * f4 + 1] += xk * wv.y;
            acc[4 * f4 + 2] += xk * wv.z;
            acc[4 * f4 + 3] += xk * wv.w;
        }
    }

    float di = dinv[i];
    float4* hp = reinterpret_cast<float4*>(ht + (size_t)i * 64);
    #pragma unroll
    for (int f4 = 0; f4 < 16; ++f4) {
        float4 v;
        v.x = acc[4 * f4 + 0] * di; v.y = acc[4 * f4 + 1] * di;
        v.z = acc[4 * f4 + 2] * di; v.w = acc[4 * f4 + 3] * di;
        hp[f4] = v;
    }
}

// ---------------- layer 1 gather (+ fin1 fused): wave per node, lane = feature ----------------

__global__ __launch_bounds__(256) void k_gather1(const float* __restrict__ ht,
                                                 const int* __restrict__ rs,
                                                 const int* __restrict__ csr,
                                                 const float* __restrict__ dinv,
                                                 const float* __restrict__ b1,
                                                 float* __restrict__ h) {
    int wid = (blockIdx.x * 256 + threadIdx.x) >> 6;
    if (wid >= NN) return;
    int f = threadIdx.x & 63;
    int i = wid;
    int beg = rs[i], end = rs[i + 1];

    float acc = ht[(size_t)i * 64 + f];      // self term
    int j = beg;
    for (; j + 1 < end; j += 2) {
        int s0 = csr[j], s1 = csr[j + 1];
        float a0 = ht[(size_t)s0 * 64 + f];
        float a1 = ht[(size_t)s1 * 64 + f];
        acc += a0; acc += a1;
    }
    if (j < end) acc += ht[(size_t)csr[j] * 64 + f];

    float v = dinv[i] * acc + b1[f];
    h[(size_t)i * 64 + f] = fmaxf(v, 0.f);
}

// ---------------- layer 2 GEMM: ht2 = (h @ W2) * dinv, stride 33 ----------------

__global__ __launch_bounds__(256) void k_gemm2(const float* __restrict__ h,
                                               const float* __restrict__ W2,
                                               const float* __restrict__ dinv,
                                               float* __restrict__ ht2) {
    __shared__ float w[64 * 36];   // padded stride 36 for float4 alignment
    for (int t = threadIdx.x; t < 64 * 36; t += 256) {
        int k = t / 36, c = t - k * 36;
        w[t] = (c < D2) ? W2[k * D2 + c] : 0.f;
    }
    __syncthreads();

    int i = blockIdx.x * 256 + threadIdx.x;
    if (i >= NN) return;

    float xr[64];
    const float4* xp = reinterpret_cast<const float4*>(h + (size_t)i * 64);
    #pragma unroll
    for (int q = 0; q < 16; ++q) {
        float4 v = xp[q];
        xr[4 * q + 0] = v.x; xr[4 * q + 1] = v.y;
        xr[4 * q + 2] = v.z; xr[4 * q + 3] = v.w;
    }

    float acc[36];
    #pragma unroll
    for (int c = 0; c < 36; ++c) acc[c] = 0.f;

    for (int k = 0; k < 64; ++k) {
        float xk = xr[k];
        const float4* wr = reinterpret_cast<const float4*>(w + k * 36);
        #pragma unroll
        for (int c4 = 0; c4 < 9; ++c4) {
            float4 wv = wr[c4];
            acc[4 * c4 + 0] += xk * wv.x;
            acc[4 * c4 + 1] += xk * wv.y;
            acc[4 * c4 + 2] += xk * wv.z;
            acc[4 * c4 + 3] += xk * wv.w;
        }
    }

    float di = dinv[i];
    float* hp = ht2 + (size_t)i * D2;
    for (int c = 0; c < D2; ++c) hp[c] = acc[c] * di;
}

// ---------------- layer 2 gather (+ epilogue fused) ----------------

__global__ __launch_bounds__(256) void k_gather2(const float* __restrict__ ht2,
                                                 const int* __restrict__ rs,
                                                 const int* __restrict__ csr,
                                                 const float* __restrict__ dinv,
                                                 const float* __restrict__ b2,
                                                 float* __restrict__ out) {
    int wid = (blockIdx.x * 256 + threadIdx.x) >> 6;
    if (wid >= NN) return;
    int f = threadIdx.x & 63;
    int i = wid;
    int beg = rs[i], end = rs[i + 1];

    float acc = (f < D2) ? ht2[(size_t)i * D2 + f] : 0.f;
    int j = beg;
    for (; j + 1 < end; j += 2) {
        int s0 = csr[j], s1 = csr[j + 1];
        float a0 = (f < D2) ? ht2[(size_t)s0 * D2 + f] : 0.f;
        float a1 = (f < D2) ? ht2[(size_t)s1 * D2 + f] : 0.f;
        acc += a0; acc += a1;
    }
    if (j < end && f < D2) acc += ht2[(size_t)csr[j] * D2 + f];

    if (f < D2) {
        float v = dinv[i] * acc + b2[f];
        if (f < 32) out[(size_t)i * 32 + f] = v;
        else        out[(size_t)NN * 32 + i] = expf(v);
    }
}

extern "C" void kernel_launch(void* const* d_in, const int* in_sizes, int n_in,
                              void* d_out, int out_size, void* d_ws, size_t ws_size,
                              hipStream_t stream) {
    const float* x  = (const float*)d_in[0];
    const float* W1 = (const float*)d_in[1];
    const float* b1 = (const float*)d_in[2];
    const float* W2 = (const float*)d_in[3];
    const float* b2 = (const float*)d_in[4];
    const int*   ei = (const int*)d_in[5];
    const int* src = ei;
    const int* dst = ei + NE;
    float* out = (float*)d_out;

    // workspace layout:
    //   ints:   cnt[NN] | rs[NN+1] | cursor[NN] | bsum[NB] | boff[NB] | csr[NE]
    //   floats: dinv[NN] | ht1/h A[NN*64] | h B[NN*64] | ht2[NN*33]
    char* p = (char*)d_ws;
    int* cnt    = (int*)p;              p += sizeof(int) * NN;
    int* rs     = (int*)p;              p += sizeof(int) * (NN + 1);
    int* cursor = (int*)p;              p += sizeof(int) * NN;
    int* bsum   = (int*)p;              p += sizeof(int) * NB;
    int* boff   = (int*)p;              p += sizeof(int) * NB;
    p = (char*)(((uintptr_t)p + 255) & ~(uintptr_t)255);
    int* csr    = (int*)p;              p += sizeof(int) * NE;
    p = (char*)(((uintptr_t)p + 255) & ~(uintptr_t)255);
    float* dinv = (float*)p;            p += sizeof(float) * NN;
    p = (char*)(((uintptr_t)p + 255) & ~(uintptr_t)255);
    float* bufA = (float*)p;            p += sizeof(float) * (size_t)NN * 64;  // ht1
    float* bufB = (float*)p;            p += sizeof(float) * (size_t)NN * 64;  // h
    float* bufC = (float*)p;            p += sizeof(float) * (size_t)NN * D2;  // ht2

    // ---- CSR build ----
    hipMemsetAsync(cnt, 0, sizeof(int) * NN, stream);
    hipMemsetAsync(cursor, 0, sizeof(int) * NN, stream);
    k_cnt<<<(NE + 255) / 256, 256, 0, stream>>>(dst, cnt);
    k_dinv<<<(NN + 255) / 256, 256, 0, stream>>>(cnt, dinv);
    k_blocksum<<<NB, 256, 0, stream>>>(cnt, bsum);
    k_scanbsum<<<1, 128, 0, stream>>>(bsum, boff);
    k_scanfinal<<<NB, 256, 0, stream>>>(cnt, boff, rs);
    k_bin<<<(NE + 255) / 256, 256, 0, stream>>>(src, dst, rs, cursor, csr);

    // ---- layer 1 ----
    k_gemm1<<<(NN + 255) / 256, 256, 0, stream>>>(x, W1, dinv, bufA);
    k_gather1<<<(NN * 64 + 255) / 256, 256, 0, stream>>>(bufA, rs, csr, dinv, b1, bufB);

    // ---- layer 2 ----
    k_gemm2<<<(NN + 255) / 256, 256, 0, stream>>>(bufB, W2, dinv, bufC);
    k_gather2<<<(NN * 64 + 255) / 256, 256, 0, stream>>>(bufC, rs, csr, dinv, b2, out);
}

// Round 3
// 377.338 us; speedup vs baseline: 2.2345x; 1.2648x over previous
//
#include <hip/hip_runtime.h>
#include <hip/hip_bf16.h>

// GCN 2-layer: N=100000 nodes, E=1600000 edges, 64 -> 64(relu) -> 33.
// out = [pos (N*32) | mass (N*1)], float32.
//
// ht[i] = (x@W)[i] * dinv[i]
// gcnconv(x)[i] = dinv[i] * ( sum_{e: dst=i} ht[src[e]] + ht[i] ) + b
//
// R3: gather tables in bf16 (halve random-read lines), quad-neighbor all-lane
// gathers (4 rows/wave/iter, x2 unrolled), ht2 split into aligned pos(bf16)
// + mass(f32) tables.

constexpr int NN = 100000;
constexpr int NE = 1600000;
constexpr int D2 = 33;   // OUT + 1

constexpr int SCAN_CHUNK = 1024;                       // 256 thr x 4 items
constexpr int NB = (NN + SCAN_CHUNK - 1) / SCAN_CHUNK; // 98 (<=128)

// ---------------- bf16 helpers ----------------

__device__ inline float bflo(unsigned w) { union { unsigned u; float f; } c; c.u = w << 16; return c.f; }
__device__ inline float bfhi(unsigned w) { union { unsigned u; float f; } c; c.u = w & 0xffff0000u; return c.f; }
__device__ inline unsigned f2bf_bits(float f) {
    __hip_bfloat16 h = __float2bfloat16(f);
    unsigned short u; __builtin_memcpy(&u, &h, 2); return (unsigned)u;
}
__device__ inline unsigned pack2(float a, float b) { return f2bf_bits(a) | (f2bf_bits(b) << 16); }

// ---------------- degree count (int) ----------------

__global__ void k_cnt(const int* __restrict__ dst, int* __restrict__ cnt) {
    int e = blockIdx.x * blockDim.x + threadIdx.x;
    if (e < NE) atomicAdd(&cnt[dst[e]], 1);
}

__global__ void k_dinv(const int* __restrict__ cnt, float* __restrict__ dinv) {
    int i = blockIdx.x * blockDim.x + threadIdx.x;
    if (i < NN) dinv[i] = rsqrtf((float)cnt[i] + 1.0f);
}

// ---------------- exclusive scan of cnt -> rs[0..NN] ----------------

__global__ void k_blocksum(const int* __restrict__ cnt, int* __restrict__ bsum) {
    __shared__ int sh[256];
    int base = blockIdx.x * SCAN_CHUNK + threadIdx.x * 4;
    int s = 0;
    #pragma unroll
    for (int k = 0; k < 4; ++k) { int i = base + k; if (i < NN) s += cnt[i]; }
    sh[threadIdx.x] = s; __syncthreads();
    for (int off = 128; off > 0; off >>= 1) {
        if (threadIdx.x < off) sh[threadIdx.x] += sh[threadIdx.x + off];
        __syncthreads();
    }
    if (threadIdx.x == 0) bsum[blockIdx.x] = sh[0];
}

__global__ void k_scanbsum(const int* __restrict__ bsum, int* __restrict__ boff) {
    __shared__ int sh[128];
    int t = threadIdx.x;
    int v = (t < NB) ? bsum[t] : 0;
    sh[t] = v; __syncthreads();
    for (int off = 1; off < 128; off <<= 1) {
        int add = (t >= off) ? sh[t - off] : 0;
        __syncthreads();
        sh[t] += add;
        __syncthreads();
    }
    if (t < NB) boff[t] = sh[t] - v;   // exclusive
}

__global__ void k_scanfinal(const int* __restrict__ cnt, const int* __restrict__ boff,
                            int* __restrict__ rs) {
    __shared__ int sh[256];
    int t = threadIdx.x;
    int base = blockIdx.x * SCAN_CHUNK + t * 4;
    int v[4]; int s = 0;
    #pragma unroll
    for (int k = 0; k < 4; ++k) { int i = base + k; v[k] = (i < NN) ? cnt[i] : 0; s += v[k]; }
    sh[t] = s; __syncthreads();
    for (int off = 1; off < 256; off <<= 1) {
        int add = (t >= off) ? sh[t - off] : 0;
        __syncthreads();
        sh[t] += add;
        __syncthreads();
    }
    int ex = sh[t] - s + boff[blockIdx.x];
    #pragma unroll
    for (int k = 0; k < 4; ++k) {
        int i = base + k;
        if (i < NN) { rs[i] = ex; ex += v[k]; if (i == NN - 1) rs[NN] = ex; }
    }
}

// ---------------- bin edges into CSR ----------------

__global__ void k_bin(const int* __restrict__ src, const int* __restrict__ dst,
                      const int* __restrict__ rs, int* __restrict__ cursor,
                      int* __restrict__ csr) {
    int e = blockIdx.x * blockDim.x + threadIdx.x;
    if (e < NE) {
        int d = dst[e];
        int p = atomicAdd(&cursor[d], 1);
        csr[rs[d] + p] = src[e];
    }
}

// ---------------- layer 1 GEMM: ht1 = bf16( (x @ W1) * dinv ) ----------------

__global__ __launch_bounds__(256) void k_gemm1(const float* __restrict__ x,
                                               const float* __restrict__ W1,
                                               const float* __restrict__ dinv,
                                               unsigned short* __restrict__ ht1) {
    __shared__ float w[64 * 64];
    for (int t = threadIdx.x; t < 64 * 64; t += 256) w[t] = W1[t];
    __syncthreads();

    int i = blockIdx.x * 256 + threadIdx.x;
    if (i >= NN) return;

    float xr[64];
    const float4* xp = reinterpret_cast<const float4*>(x + (size_t)i * 64);
    #pragma unroll
    for (int q = 0; q < 16; ++q) {
        float4 v = xp[q];
        xr[4 * q + 0] = v.x; xr[4 * q + 1] = v.y;
        xr[4 * q + 2] = v.z; xr[4 * q + 3] = v.w;
    }

    float acc[64];
    #pragma unroll
    for (int f = 0; f < 64; ++f) acc[f] = 0.f;

    for (int k = 0; k < 64; ++k) {
        float xk = xr[k];
        const float4* wr = reinterpret_cast<const float4*>(w + k * 64);
        #pragma unroll
        for (int f4 = 0; f4 < 16; ++f4) {
            float4 wv = wr[f4];
            acc[4 * f4 + 0] += xk * wv.x;
            acc[4 * f4 + 1] += xk * wv.y;
            acc[4 * f4 + 2] += xk * wv.z;
            acc[4 * f4 + 3] += xk * wv.w;
        }
    }

    float di = dinv[i];
    uint4* hp = reinterpret_cast<uint4*>(ht1 + (size_t)i * 64);
    #pragma unroll
    for (int q = 0; q < 8; ++q) {
        uint4 v;
        v.x = pack2(acc[8 * q + 0] * di, acc[8 * q + 1] * di);
        v.y = pack2(acc[8 * q + 2] * di, acc[8 * q + 3] * di);
        v.z = pack2(acc[8 * q + 4] * di, acc[8 * q + 5] * di);
        v.w = pack2(acc[8 * q + 6] * di, acc[8 * q + 7] * di);
        hp[q] = v;
    }
}

// ---------------- layer 1 gather: wave/node, 4 neighbor slots x 16 feat-groups ----------------

__global__ __launch_bounds__(256) void k_gather1(const unsigned short* __restrict__ ht,
                                                 const int* __restrict__ rs,
                                                 const int* __restrict__ csr,
                                                 const float* __restrict__ dinv,
                                                 const float* __restrict__ b1,
                                                 float* __restrict__ h) {
    int wid = (blockIdx.x * 256 + threadIdx.x) >> 6;
    if (wid >= NN) return;
    int lane = threadIdx.x & 63;
    int q = lane >> 4;     // neighbor slot 0..3
    int g = lane & 15;     // feats 4g..4g+3
    int beg = rs[wid], end = rs[wid + 1];

    float a0 = 0.f, a1 = 0.f, a2 = 0.f, a3 = 0.f;
    int j = beg + q;
    for (; j + 4 < end; j += 8) {
        int s  = csr[j];
        int s2 = csr[j + 4];
        uint2 w  = *reinterpret_cast<const uint2*>(ht + (size_t)s  * 64 + 4 * g);
        uint2 w2 = *reinterpret_cast<const uint2*>(ht + (size_t)s2 * 64 + 4 * g);
        a0 += bflo(w.x) + bflo(w2.x); a1 += bfhi(w.x) + bfhi(w2.x);
        a2 += bflo(w.y) + bflo(w2.y); a3 += bfhi(w.y) + bfhi(w2.y);
    }
    for (; j < end; j += 4) {
        int s = csr[j];
        uint2 w = *reinterpret_cast<const uint2*>(ht + (size_t)s * 64 + 4 * g);
        a0 += bflo(w.x); a1 += bfhi(w.x); a2 += bflo(w.y); a3 += bfhi(w.y);
    }

    a0 += __shfl_xor(a0, 16); a0 += __shfl_xor(a0, 32);
    a1 += __shfl_xor(a1, 16); a1 += __shfl_xor(a1, 32);
    a2 += __shfl_xor(a2, 16); a2 += __shfl_xor(a2, 32);
    a3 += __shfl_xor(a3, 16); a3 += __shfl_xor(a3, 32);

    if (q == 0) {
        uint2 sw = *reinterpret_cast<const uint2*>(ht + (size_t)wid * 64 + 4 * g);
        a0 += bflo(sw.x); a1 += bfhi(sw.x); a2 += bflo(sw.y); a3 += bfhi(sw.y);
        float di = dinv[wid];
        float4 v;
        v.x = fmaxf(di * a0 + b1[4 * g + 0], 0.f);
        v.y = fmaxf(di * a1 + b1[4 * g + 1], 0.f);
        v.z = fmaxf(di * a2 + b1[4 * g + 2], 0.f);
        v.w = fmaxf(di * a3 + b1[4 * g + 3], 0.f);
        *reinterpret_cast<float4*>(h + (size_t)wid * 64 + 4 * g) = v;
    }
}

// ---------------- layer 2 GEMM: htp = bf16((h@W2)[:, :32]*dinv), htm = f32 col 32 ----------------

__global__ __launch_bounds__(256) void k_gemm2(const float* __restrict__ h,
                                               const float* __restrict__ W2,
                                               const float* __restrict__ dinv,
                                               unsigned short* __restrict__ htp,
                                               float* __restrict__ htm) {
    __shared__ float w[64 * 36];   // padded stride 36 for float4 alignment
    for (int t = threadIdx.x; t < 64 * 36; t += 256) {
        int k = t / 36, c = t - k * 36;
        w[t] = (c < D2) ? W2[k * D2 + c] : 0.f;
    }
    __syncthreads();

    int i = blockIdx.x * 256 + threadIdx.x;
    if (i >= NN) return;

    float xr[64];
    const float4* xp = reinterpret_cast<const float4*>(h + (size_t)i * 64);
    #pragma unroll
    for (int q = 0; q < 16; ++q) {
        float4 v = xp[q];
        xr[4 * q + 0] = v.x; xr[4 * q + 1] = v.y;
        xr[4 * q + 2] = v.z; xr[4 * q + 3] = v.w;
    }

    float acc[36];
    #pragma unroll
    for (int c = 0; c < 36; ++c) acc[c] = 0.f;

    for (int k = 0; k < 64; ++k) {
        float xk = xr[k];
        const float4* wr = reinterpret_cast<const float4*>(w + k * 36);
        #pragma unroll
        for (int c4 = 0; c4 < 9; ++c4) {
            float4 wv = wr[c4];
            acc[4 * c4 + 0] += xk * wv.x;
            acc[4 * c4 + 1] += xk * wv.y;
            acc[4 * c4 + 2] += xk * wv.z;
            acc[4 * c4 + 3] += xk * wv.w;
        }
    }

    float di = dinv[i];
    uint4* pp = reinterpret_cast<uint4*>(htp + (size_t)i * 32);
    #pragma unroll
    for (int q = 0; q < 4; ++q) {
        uint4 v;
        v.x = pack2(acc[8 * q + 0] * di, acc[8 * q + 1] * di);
        v.y = pack2(acc[8 * q + 2] * di, acc[8 * q + 3] * di);
        v.z = pack2(acc[8 * q + 4] * di, acc[8 * q + 5] * di);
        v.w = pack2(acc[8 * q + 6] * di, acc[8 * q + 7] * di);
        pp[q] = v;
    }
    htm[i] = acc[32] * di;
}

// ---------------- layer 2 gather (+ epilogue): 4 slots x 16 feat-groups + mass ----------------

__global__ __launch_bounds__(256) void k_gather2(const unsigned short* __restrict__ htp,
                                                 const float* __restrict__ htm,
                                                 const int* __restrict__ rs,
                                                 const int* __restrict__ csr,
                                                 const float* __restrict__ dinv,
                                                 const float* __restrict__ b2,
                                                 float* __restrict__ out) {
    int wid = (blockIdx.x * 256 + threadIdx.x) >> 6;
    if (wid >= NN) return;
    int lane = threadIdx.x & 63;
    int q = lane >> 4;     // neighbor slot
    int g = lane & 15;     // feats 2g,2g+1
    int beg = rs[wid], end = rs[wid + 1];

    float a0 = 0.f, a1 = 0.f;
    int j = beg + q;
    for (; j + 4 < end; j += 8) {
        int s  = csr[j];
        int s2 = csr[j + 4];
        unsigned w  = *reinterpret_cast<const unsigned*>(htp + (size_t)s  * 32 + 2 * g);
        unsigned w2 = *reinterpret_cast<const unsigned*>(htp + (size_t)s2 * 32 + 2 * g);
        a0 += bflo(w) + bflo(w2); a1 += bfhi(w) + bfhi(w2);
    }
    for (; j < end; j += 4) {
        int s = csr[j];
        unsigned w = *reinterpret_cast<const unsigned*>(htp + (size_t)s * 32 + 2 * g);
        a0 += bflo(w); a1 += bfhi(w);
    }

    // mass column: per-lane strided, f32 table
    float m = 0.f;
    for (int jm = beg + lane; jm < end; jm += 64) m += htm[csr[jm]];

    a0 += __shfl_xor(a0, 16); a0 += __shfl_xor(a0, 32);
    a1 += __shfl_xor(a1, 16); a1 += __shfl_xor(a1, 32);
    m += __shfl_xor(m, 1);  m += __shfl_xor(m, 2);  m += __shfl_xor(m, 4);
    m += __shfl_xor(m, 8);  m += __shfl_xor(m, 16); m += __shfl_xor(m, 32);

    float di = dinv[wid];
    if (q == 0) {
        unsigned sw = *reinterpret_cast<const unsigned*>(htp + (size_t)wid * 32 + 2 * g);
        a0 += bflo(sw); a1 += bfhi(sw);
        float2 v;
        v.x = di * a0 + b2[2 * g + 0];
        v.y = di * a1 + b2[2 * g + 1];
        *reinterpret_cast<float2*>(out + (size_t)wid * 32 + 2 * g) = v;
    }
    if (lane == 0) {
        float v = di * (m + htm[wid]) + b2[32];
        out[(size_t)NN * 32 + wid] = expf(v);
    }
}

extern "C" void kernel_launch(void* const* d_in, const int* in_sizes, int n_in,
                              void* d_out, int out_size, void* d_ws, size_t ws_size,
                              hipStream_t stream) {
    const float* x  = (const float*)d_in[0];
    const float* W1 = (const float*)d_in[1];
    const float* b1 = (const float*)d_in[2];
    const float* W2 = (const float*)d_in[3];
    const float* b2 = (const float*)d_in[4];
    const int*   ei = (const int*)d_in[5];
    const int* src = ei;
    const int* dst = ei + NE;
    float* out = (float*)d_out;

    // workspace layout
    char* p = (char*)d_ws;
    int* cnt    = (int*)p;              p += sizeof(int) * NN;
    int* rs     = (int*)p;              p += sizeof(int) * (NN + 1);
    int* cursor = (int*)p;              p += sizeof(int) * NN;
    int* bsum   = (int*)p;              p += sizeof(int) * NB;
    int* boff   = (int*)p;              p += sizeof(int) * NB;
    p = (char*)(((uintptr_t)p + 255) & ~(uintptr_t)255);
    int* csr    = (int*)p;              p += sizeof(int) * NE;
    p = (char*)(((uintptr_t)p + 255) & ~(uintptr_t)255);
    float* dinv = (float*)p;            p += sizeof(float) * NN;
    p = (char*)(((uintptr_t)p + 255) & ~(uintptr_t)255);
    unsigned short* ht1 = (unsigned short*)p; p += sizeof(unsigned short) * (size_t)NN * 64;
    p = (char*)(((uintptr_t)p + 255) & ~(uintptr_t)255);
    float* h    = (float*)p;            p += sizeof(float) * (size_t)NN * 64;
    p = (char*)(((uintptr_t)p + 255) & ~(uintptr_t)255);
    unsigned short* htp = (unsigned short*)p; p += sizeof(unsigned short) * (size_t)NN * 32;
    p = (char*)(((uintptr_t)p + 255) & ~(uintptr_t)255);
    float* htm  = (float*)p;            p += sizeof(float) * NN;

    // ---- CSR build ----
    hipMemsetAsync(cnt, 0, sizeof(int) * NN, stream);
    hipMemsetAsync(cursor, 0, sizeof(int) * NN, stream);
    k_cnt<<<(NE + 255) / 256, 256, 0, stream>>>(dst, cnt);
    k_dinv<<<(NN + 255) / 256, 256, 0, stream>>>(cnt, dinv);
    k_blocksum<<<NB, 256, 0, stream>>>(cnt, bsum);
    k_scanbsum<<<1, 128, 0, stream>>>(bsum, boff);
    k_scanfinal<<<NB, 256, 0, stream>>>(cnt, boff, rs);
    k_bin<<<(NE + 255) / 256, 256, 0, stream>>>(src, dst, rs, cursor, csr);

    // ---- layer 1 ----
    k_gemm1<<<(NN + 255) / 256, 256, 0, stream>>>(x, W1, dinv, ht1);
    k_gather1<<<(NN * 64 + 255) / 256, 256, 0, stream>>>(ht1, rs, csr, dinv, b1, h);

    // ---- layer 2 ----
    k_gemm2<<<(NN + 255) / 256, 256, 0, stream>>>(h, W2, dinv, htp, htm);
    k_gather2<<<(NN * 64 + 255) / 256, 256, 0, stream>>>(htp, htm, rs, csr, dinv, b2, out);
}

// Round 4
// 342.575 us; speedup vs baseline: 2.4613x; 1.1015x over previous
//
#include <hip/hip_runtime.h>
#include <hip/hip_bf16.h>

// GCN 2-layer: N=100000 nodes, E=1600000 edges, 64 -> 64(relu) -> 33.
// out = [pos (N*32) | mass (N*1)], float32.
//
// ht[i] = (x@W)[i] * dinv[i]
// gcnconv(x)[i] = dinv[i] * ( sum_{e: dst=i} ht[src[e]] + ht[i] ) + b
//
// R4: (a) k_bin -> 8-pass dst-range bucketing (active csr region 0.8MB per
// pass stays L2-resident; kills the 107MB partial-line writeback storm);
// (b) gathers use 8 neighbor slots/wave (uint4 / uint2 per lane), 16 rows
// in flight, to attack latency-boundness.

constexpr int NN = 100000;
constexpr int NE = 1600000;
constexpr int D2 = 33;   // OUT + 1

constexpr int SCAN_CHUNK = 1024;                       // 256 thr x 4 items
constexpr int NB = (NN + SCAN_CHUNK - 1) / SCAN_CHUNK; // 98 (<=128)
constexpr int BIN_PASSES = 8;

// ---------------- bf16 helpers ----------------

__device__ inline float bflo(unsigned w) { union { unsigned u; float f; } c; c.u = w << 16; return c.f; }
__device__ inline float bfhi(unsigned w) { union { unsigned u; float f; } c; c.u = w & 0xffff0000u; return c.f; }
__device__ inline unsigned f2bf_bits(float f) {
    __hip_bfloat16 h = __float2bfloat16(f);
    unsigned short u; __builtin_memcpy(&u, &h, 2); return (unsigned)u;
}
__device__ inline unsigned pack2(float a, float b) { return f2bf_bits(a) | (f2bf_bits(b) << 16); }

// ---------------- degree count (int) ----------------

__global__ void k_cnt(const int* __restrict__ dst, int* __restrict__ cnt) {
    int e = blockIdx.x * blockDim.x + threadIdx.x;
    if (e < NE) atomicAdd(&cnt[dst[e]], 1);
}

__global__ void k_dinv(const int* __restrict__ cnt, float* __restrict__ dinv) {
    int i = blockIdx.x * blockDim.x + threadIdx.x;
    if (i < NN) dinv[i] = rsqrtf((float)cnt[i] + 1.0f);
}

// ---------------- exclusive scan of cnt -> rs[0..NN] ----------------

__global__ void k_blocksum(const int* __restrict__ cnt, int* __restrict__ bsum) {
    __shared__ int sh[256];
    int base = blockIdx.x * SCAN_CHUNK + threadIdx.x * 4;
    int s = 0;
    #pragma unroll
    for (int k = 0; k < 4; ++k) { int i = base + k; if (i < NN) s += cnt[i]; }
    sh[threadIdx.x] = s; __syncthreads();
    for (int off = 128; off > 0; off >>= 1) {
        if (threadIdx.x < off) sh[threadIdx.x] += sh[threadIdx.x + off];
        __syncthreads();
    }
    if (threadIdx.x == 0) bsum[blockIdx.x] = sh[0];
}

__global__ void k_scanbsum(const int* __restrict__ bsum, int* __restrict__ boff) {
    __shared__ int sh[128];
    int t = threadIdx.x;
    int v = (t < NB) ? bsum[t] : 0;
    sh[t] = v; __syncthreads();
    for (int off = 1; off < 128; off <<= 1) {
        int add = (t >= off) ? sh[t - off] : 0;
        __syncthreads();
        sh[t] += add;
        __syncthreads();
    }
    if (t < NB) boff[t] = sh[t] - v;   // exclusive
}

__global__ void k_scanfinal(const int* __restrict__ cnt, const int* __restrict__ boff,
                            int* __restrict__ rs) {
    __shared__ int sh[256];
    int t = threadIdx.x;
    int base = blockIdx.x * SCAN_CHUNK + t * 4;
    int v[4]; int s = 0;
    #pragma unroll
    for (int k = 0; k < 4; ++k) { int i = base + k; v[k] = (i < NN) ? cnt[i] : 0; s += v[k]; }
    sh[t] = s; __syncthreads();
    for (int off = 1; off < 256; off <<= 1) {
        int add = (t >= off) ? sh[t - off] : 0;
        __syncthreads();
        sh[t] += add;
        __syncthreads();
    }
    int ex = sh[t] - s + boff[blockIdx.x];
    #pragma unroll
    for (int k = 0; k < 4; ++k) {
        int i = base + k;
        if (i < NN) { rs[i] = ex; ex += v[k]; if (i == NN - 1) rs[NN] = ex; }
    }
}

// ---------------- bin edges into CSR: 8 dst-range passes for L2 locality ----------------

__global__ __launch_bounds__(256) void k_bin_mp(const int* __restrict__ src,
                                                const int* __restrict__ dst,
                                                const int* __restrict__ rs,
                                                int* __restrict__ cursor,
                                                int* __restrict__ csr) {
    int stride = gridDim.x * blockDim.x;
    int tid = blockIdx.x * blockDim.x + threadIdx.x;
    constexpr int RANGE = (NN + BIN_PASSES - 1) / BIN_PASSES;  // 12500
    for (int pass = 0; pass < BIN_PASSES; ++pass) {
        int lo = pass * RANGE;
        int hi = min(lo + RANGE, NN);
        for (int e = tid; e < NE; e += stride) {
            int d = dst[e];
            if (d >= lo && d < hi) {
                int p = atomicAdd(&cursor[d], 1);
                csr[rs[d] + p] = src[e];
            }
        }
    }
}

// ---------------- layer 1 GEMM: ht1 = bf16( (x @ W1) * dinv ) ----------------

__global__ __launch_bounds__(256) void k_gemm1(const float* __restrict__ x,
                                               const float* __restrict__ W1,
                                               const float* __restrict__ dinv,
                                               unsigned short* __restrict__ ht1) {
    __shared__ float w[64 * 64];
    for (int t = threadIdx.x; t < 64 * 64; t += 256) w[t] = W1[t];
    __syncthreads();

    int i = blockIdx.x * 256 + threadIdx.x;
    if (i >= NN) return;

    float xr[64];
    const float4* xp = reinterpret_cast<const float4*>(x + (size_t)i * 64);
    #pragma unroll
    for (int q = 0; q < 16; ++q) {
        float4 v = xp[q];
        xr[4 * q + 0] = v.x; xr[4 * q + 1] = v.y;
        xr[4 * q + 2] = v.z; xr[4 * q + 3] = v.w;
    }

    float acc[64];
    #pragma unroll
    for (int f = 0; f < 64; ++f) acc[f] = 0.f;

    for (int k = 0; k < 64; ++k) {
        float xk = xr[k];
        const float4* wr = reinterpret_cast<const float4*>(w + k * 64);
        #pragma unroll
        for (int f4 = 0; f4 < 16; ++f4) {
            float4 wv = wr[f4];
            acc[4 * f4 + 0] += xk * wv.x;
            acc[4 * f4 + 1] += xk * wv.y;
            acc[4 * f4 + 2] += xk * wv.z;
            acc[4 * f4 + 3] += xk * wv.w;
        }
    }

    float di = dinv[i];
    uint4* hp = reinterpret_cast<uint4*>(ht1 + (size_t)i * 64);
    #pragma unroll
    for (int q = 0; q < 8; ++q) {
        uint4 v;
        v.x = pack2(acc[8 * q + 0] * di, acc[8 * q + 1] * di);
        v.y = pack2(acc[8 * q + 2] * di, acc[8 * q + 3] * di);
        v.z = pack2(acc[8 * q + 4] * di, acc[8 * q + 5] * di);
        v.w = pack2(acc[8 * q + 6] * di, acc[8 * q + 7] * di);
        hp[q] = v;
    }
}

// ---------------- layer 1 gather: wave/node, 8 slots x 8 feat-groups (uint4) ----------------

__global__ __launch_bounds__(256) void k_gather1(const unsigned short* __restrict__ ht,
                                                 const int* __restrict__ rs,
                                                 const int* __restrict__ csr,
                                                 const float* __restrict__ dinv,
                                                 const float* __restrict__ b1,
                                                 float* __restrict__ h) {
    int wid = (blockIdx.x * 256 + threadIdx.x) >> 6;
    if (wid >= NN) return;
    int lane = threadIdx.x & 63;
    int q = lane >> 3;     // neighbor slot 0..7
    int g = lane & 7;      // feats 8g..8g+7
    int beg = rs[wid], end = rs[wid + 1];

    float a0 = 0.f, a1 = 0.f, a2 = 0.f, a3 = 0.f;
    float a4 = 0.f, a5 = 0.f, a6 = 0.f, a7 = 0.f;
    int j = beg + q;
    for (; j + 8 < end; j += 16) {
        int s  = csr[j];
        int s2 = csr[j + 8];
        uint4 w  = *reinterpret_cast<const uint4*>(ht + (size_t)s  * 64 + 8 * g);
        uint4 w2 = *reinterpret_cast<const uint4*>(ht + (size_t)s2 * 64 + 8 * g);
        a0 += bflo(w.x) + bflo(w2.x); a1 += bfhi(w.x) + bfhi(w2.x);
        a2 += bflo(w.y) + bflo(w2.y); a3 += bfhi(w.y) + bfhi(w2.y);
        a4 += bflo(w.z) + bflo(w2.z); a5 += bfhi(w.z) + bfhi(w2.z);
        a6 += bflo(w.w) + bflo(w2.w); a7 += bfhi(w.w) + bfhi(w2.w);
    }
    for (; j < end; j += 8) {
        int s = csr[j];
        uint4 w = *reinterpret_cast<const uint4*>(ht + (size_t)s * 64 + 8 * g);
        a0 += bflo(w.x); a1 += bfhi(w.x); a2 += bflo(w.y); a3 += bfhi(w.y);
        a4 += bflo(w.z); a5 += bfhi(w.z); a6 += bflo(w.w); a7 += bfhi(w.w);
    }

    #pragma unroll
    for (int off = 8; off < 64; off <<= 1) {
        a0 += __shfl_xor(a0, off); a1 += __shfl_xor(a1, off);
        a2 += __shfl_xor(a2, off); a3 += __shfl_xor(a3, off);
        a4 += __shfl_xor(a4, off); a5 += __shfl_xor(a5, off);
        a6 += __shfl_xor(a6, off); a7 += __shfl_xor(a7, off);
    }

    if (q == 0) {
        uint4 sw = *reinterpret_cast<const uint4*>(ht + (size_t)wid * 64 + 8 * g);
        a0 += bflo(sw.x); a1 += bfhi(sw.x); a2 += bflo(sw.y); a3 += bfhi(sw.y);
        a4 += bflo(sw.z); a5 += bfhi(sw.z); a6 += bflo(sw.w); a7 += bfhi(sw.w);
        float di = dinv[wid];
        const float4* bp = reinterpret_cast<const float4*>(b1 + 8 * g);
        float4 bA = bp[0], bB = bp[1];
        float4 vA, vB;
        vA.x = fmaxf(di * a0 + bA.x, 0.f); vA.y = fmaxf(di * a1 + bA.y, 0.f);
        vA.z = fmaxf(di * a2 + bA.z, 0.f); vA.w = fmaxf(di * a3 + bA.w, 0.f);
        vB.x = fmaxf(di * a4 + bB.x, 0.f); vB.y = fmaxf(di * a5 + bB.y, 0.f);
        vB.z = fmaxf(di * a6 + bB.z, 0.f); vB.w = fmaxf(di * a7 + bB.w, 0.f);
        float4* hp = reinterpret_cast<float4*>(h + (size_t)wid * 64 + 8 * g);
        hp[0] = vA; hp[1] = vB;
    }
}

// ---------------- layer 2 GEMM: htp = bf16((h@W2)[:, :32]*dinv), htm = f32 col 32 ----------------

__global__ __launch_bounds__(256) void k_gemm2(const float* __restrict__ h,
                                               const float* __restrict__ W2,
                                               const float* __restrict__ dinv,
                                               unsigned short* __restrict__ htp,
                                               float* __restrict__ htm) {
    __shared__ float w[64 * 36];   // padded stride 36 for float4 alignment
    for (int t = threadIdx.x; t < 64 * 36; t += 256) {
        int k = t / 36, c = t - k * 36;
        w[t] = (c < D2) ? W2[k * D2 + c] : 0.f;
    }
    __syncthreads();

    int i = blockIdx.x * 256 + threadIdx.x;
    if (i >= NN) return;

    float xr[64];
    const float4* xp = reinterpret_cast<const float4*>(h + (size_t)i * 64);
    #pragma unroll
    for (int q = 0; q < 16; ++q) {
        float4 v = xp[q];
        xr[4 * q + 0] = v.x; xr[4 * q + 1] = v.y;
        xr[4 * q + 2] = v.z; xr[4 * q + 3] = v.w;
    }

    float acc[36];
    #pragma unroll
    for (int c = 0; c < 36; ++c) acc[c] = 0.f;

    for (int k = 0; k < 64; ++k) {
        float xk = xr[k];
        const float4* wr = reinterpret_cast<const float4*>(w + k * 36);
        #pragma unroll
        for (int c4 = 0; c4 < 9; ++c4) {
            float4 wv = wr[c4];
            acc[4 * c4 + 0] += xk * wv.x;
            acc[4 * c4 + 1] += xk * wv.y;
            acc[4 * c4 + 2] += xk * wv.z;
            acc[4 * c4 + 3] += xk * wv.w;
        }
    }

    float di = dinv[i];
    uint4* pp = reinterpret_cast<uint4*>(htp + (size_t)i * 32);
    #pragma unroll
    for (int q = 0; q < 4; ++q) {
        uint4 v;
        v.x = pack2(acc[8 * q + 0] * di, acc[8 * q + 1] * di);
        v.y = pack2(acc[8 * q + 2] * di, acc[8 * q + 3] * di);
        v.z = pack2(acc[8 * q + 4] * di, acc[8 * q + 5] * di);
        v.w = pack2(acc[8 * q + 6] * di, acc[8 * q + 7] * di);
        pp[q] = v;
    }
    htm[i] = acc[32] * di;
}

// ---------------- layer 2 gather (+ epilogue): 8 slots x 8 feat-groups (uint2) + mass ----------------

__global__ __launch_bounds__(256) void k_gather2(const unsigned short* __restrict__ htp,
                                                 const float* __restrict__ htm,
                                                 const int* __restrict__ rs,
                                                 const int* __restrict__ csr,
                                                 const float* __restrict__ dinv,
                                                 const float* __restrict__ b2,
                                                 float* __restrict__ out) {
    int wid = (blockIdx.x * 256 + threadIdx.x) >> 6;
    if (wid >= NN) return;
    int lane = threadIdx.x & 63;
    int q = lane >> 3;     // neighbor slot 0..7
    int g = lane & 7;      // feats 4g..4g+3
    int beg = rs[wid], end = rs[wid + 1];

    float a0 = 0.f, a1 = 0.f, a2 = 0.f, a3 = 0.f;
    int j = beg + q;
    for (; j + 8 < end; j += 16) {
        int s  = csr[j];
        int s2 = csr[j + 8];
        uint2 w  = *reinterpret_cast<const uint2*>(htp + (size_t)s  * 32 + 4 * g);
        uint2 w2 = *reinterpret_cast<const uint2*>(htp + (size_t)s2 * 32 + 4 * g);
        a0 += bflo(w.x) + bflo(w2.x); a1 += bfhi(w.x) + bfhi(w2.x);
        a2 += bflo(w.y) + bflo(w2.y); a3 += bfhi(w.y) + bfhi(w2.y);
    }
    for (; j < end; j += 8) {
        int s = csr[j];
        uint2 w = *reinterpret_cast<const uint2*>(htp + (size_t)s * 32 + 4 * g);
        a0 += bflo(w.x); a1 += bfhi(w.x); a2 += bflo(w.y); a3 += bfhi(w.y);
    }

    // mass column: per-lane strided, f32 table
    float m = 0.f;
    for (int jm = beg + lane; jm < end; jm += 64) m += htm[csr[jm]];

    #pragma unroll
    for (int off = 8; off < 64; off <<= 1) {
        a0 += __shfl_xor(a0, off); a1 += __shfl_xor(a1, off);
        a2 += __shfl_xor(a2, off); a3 += __shfl_xor(a3, off);
    }
    m += __shfl_xor(m, 1);  m += __shfl_xor(m, 2);  m += __shfl_xor(m, 4);
    m += __shfl_xor(m, 8);  m += __shfl_xor(m, 16); m += __shfl_xor(m, 32);

    float di = dinv[wid];
    if (q == 0) {
        uint2 sw = *reinterpret_cast<const uint2*>(htp + (size_t)wid * 32 + 4 * g);
        a0 += bflo(sw.x); a1 += bfhi(sw.x); a2 += bflo(sw.y); a3 += bfhi(sw.y);
        const float4* bp = reinterpret_cast<const float4*>(b2 + 4 * g);
        float4 bv = bp[0];
        float4 v;
        v.x = di * a0 + bv.x; v.y = di * a1 + bv.y;
        v.z = di * a2 + bv.z; v.w = di * a3 + bv.w;
        *reinterpret_cast<float4*>(out + (size_t)wid * 32 + 4 * g) = v;
    }
    if (lane == 0) {
        float v = di * (m + htm[wid]) + b2[32];
        out[(size_t)NN * 32 + wid] = expf(v);
    }
}

extern "C" void kernel_launch(void* const* d_in, const int* in_sizes, int n_in,
                              void* d_out, int out_size, void* d_ws, size_t ws_size,
                              hipStream_t stream) {
    const float* x  = (const float*)d_in[0];
    const float* W1 = (const float*)d_in[1];
    const float* b1 = (const float*)d_in[2];
    const float* W2 = (const float*)d_in[3];
    const float* b2 = (const float*)d_in[4];
    const int*   ei = (const int*)d_in[5];
    const int* src = ei;
    const int* dst = ei + NE;
    float* out = (float*)d_out;

    // workspace layout
    char* p = (char*)d_ws;
    int* cnt    = (int*)p;              p += sizeof(int) * NN;
    int* rs     = (int*)p;              p += sizeof(int) * (NN + 1);
    int* cursor = (int*)p;              p += sizeof(int) * NN;
    int* bsum   = (int*)p;              p += sizeof(int) * NB;
    int* boff   = (int*)p;              p += sizeof(int) * NB;
    p = (char*)(((uintptr_t)p + 255) & ~(uintptr_t)255);
    int* csr    = (int*)p;              p += sizeof(int) * NE;
    p = (char*)(((uintptr_t)p + 255) & ~(uintptr_t)255);
    float* dinv = (float*)p;            p += sizeof(float) * NN;
    p = (char*)(((uintptr_t)p + 255) & ~(uintptr_t)255);
    unsigned short* ht1 = (unsigned short*)p; p += sizeof(unsigned short) * (size_t)NN * 64;
    p = (char*)(((uintptr_t)p + 255) & ~(uintptr_t)255);
    float* h    = (float*)p;            p += sizeof(float) * (size_t)NN * 64;
    p = (char*)(((uintptr_t)p + 255) & ~(uintptr_t)255);
    unsigned short* htp = (unsigned short*)p; p += sizeof(unsigned short) * (size_t)NN * 32;
    p = (char*)(((uintptr_t)p + 255) & ~(uintptr_t)255);
    float* htm  = (float*)p;            p += sizeof(float) * NN;

    // ---- CSR build ----
    hipMemsetAsync(cnt, 0, sizeof(int) * NN, stream);
    hipMemsetAsync(cursor, 0, sizeof(int) * NN, stream);
    k_cnt<<<(NE + 255) / 256, 256, 0, stream>>>(dst, cnt);
    k_dinv<<<(NN + 255) / 256, 256, 0, stream>>>(cnt, dinv);
    k_blocksum<<<NB, 256, 0, stream>>>(cnt, bsum);
    k_scanbsum<<<1, 128, 0, stream>>>(bsum, boff);
    k_scanfinal<<<NB, 256, 0, stream>>>(cnt, boff, rs);
    k_bin_mp<<<2048, 256, 0, stream>>>(src, dst, rs, cursor, csr);

    // ---- layer 1 ----
    k_gemm1<<<(NN + 255) / 256, 256, 0, stream>>>(x, W1, dinv, ht1);
    k_gather1<<<(NN * 64 + 255) / 256, 256, 0, stream>>>(ht1, rs, csr, dinv, b1, h);

    // ---- layer 2 ----
    k_gemm2<<<(NN + 255) / 256, 256, 0, stream>>>(h, W2, dinv, htp, htm);
    k_gather2<<<(NN * 64 + 255) / 256, 256, 0, stream>>>(htp, htm, rs, csr, dinv, b2, out);
}

// Round 5
// 332.845 us; speedup vs baseline: 2.5332x; 1.0292x over previous
//
#include <hip/hip_runtime.h>
#include <hip/hip_bf16.h>

// GCN 2-layer: N=100000 nodes, E=1600000 edges, 64 -> 64(relu) -> 33.
// out = [pos (N*32) | mass (N*1)], float32.
//
// ht[i] = (x@W)[i] * dinv[i]
// gcnconv(x)[i] = dinv[i] * ( sum_{e: dst=i} ht[src[e]] + ht[i] ) + b
//
// R5: k_bin -> single-pass with dst-range partition = blockIdx%8. Under the
// round-robin block->XCD dispatch heuristic every csr line has ONE L2 owner,
// so the 16 scattered 4B stores per line merge in that L2 and write back once
// (R4 showed 8 XCDs each evicting partial copies of shared lines = 100MB).
// Correctness is independent of the mapping (ranges disjoint).

constexpr int NN = 100000;
constexpr int NE = 1600000;
constexpr int D2 = 33;   // OUT + 1

constexpr int SCAN_CHUNK = 1024;                       // 256 thr x 4 items
constexpr int NB = (NN + SCAN_CHUNK - 1) / SCAN_CHUNK; // 98 (<=128)

// ---------------- bf16 helpers ----------------

__device__ inline float bflo(unsigned w) { union { unsigned u; float f; } c; c.u = w << 16; return c.f; }
__device__ inline float bfhi(unsigned w) { union { unsigned u; float f; } c; c.u = w & 0xffff0000u; return c.f; }
__device__ inline unsigned f2bf_bits(float f) {
    __hip_bfloat16 h = __float2bfloat16(f);
    unsigned short u; __builtin_memcpy(&u, &h, 2); return (unsigned)u;
}
__device__ inline unsigned pack2(float a, float b) { return f2bf_bits(a) | (f2bf_bits(b) << 16); }

// ---------------- degree count (int) ----------------

__global__ void k_cnt(const int* __restrict__ dst, int* __restrict__ cnt) {
    int e = blockIdx.x * blockDim.x + threadIdx.x;
    if (e < NE) atomicAdd(&cnt[dst[e]], 1);
}

__global__ void k_dinv(const int* __restrict__ cnt, float* __restrict__ dinv) {
    int i = blockIdx.x * blockDim.x + threadIdx.x;
    if (i < NN) dinv[i] = rsqrtf((float)cnt[i] + 1.0f);
}

// ---------------- exclusive scan of cnt -> rs[0..NN] ----------------

__global__ void k_blocksum(const int* __restrict__ cnt, int* __restrict__ bsum) {
    __shared__ int sh[256];
    int base = blockIdx.x * SCAN_CHUNK + threadIdx.x * 4;
    int s = 0;
    #pragma unroll
    for (int k = 0; k < 4; ++k) { int i = base + k; if (i < NN) s += cnt[i]; }
    sh[threadIdx.x] = s; __syncthreads();
    for (int off = 128; off > 0; off >>= 1) {
        if (threadIdx.x < off) sh[threadIdx.x] += sh[threadIdx.x + off];
        __syncthreads();
    }
    if (threadIdx.x == 0) bsum[blockIdx.x] = sh[0];
}

__global__ void k_scanbsum(const int* __restrict__ bsum, int* __restrict__ boff) {
    __shared__ int sh[128];
    int t = threadIdx.x;
    int v = (t < NB) ? bsum[t] : 0;
    sh[t] = v; __syncthreads();
    for (int off = 1; off < 128; off <<= 1) {
        int add = (t >= off) ? sh[t - off] : 0;
        __syncthreads();
        sh[t] += add;
        __syncthreads();
    }
    if (t < NB) boff[t] = sh[t] - v;   // exclusive
}

__global__ void k_scanfinal(const int* __restrict__ cnt, const int* __restrict__ boff,
                            int* __restrict__ rs) {
    __shared__ int sh[256];
    int t = threadIdx.x;
    int base = blockIdx.x * SCAN_CHUNK + t * 4;
    int v[4]; int s = 0;
    #pragma unroll
    for (int k = 0; k < 4; ++k) { int i = base + k; v[k] = (i < NN) ? cnt[i] : 0; s += v[k]; }
    sh[t] = s; __syncthreads();
    for (int off = 1; off < 256; off <<= 1) {
        int add = (t >= off) ? sh[t - off] : 0;
        __syncthreads();
        sh[t] += add;
        __syncthreads();
    }
    int ex = sh[t] - s + boff[blockIdx.x];
    #pragma unroll
    for (int k = 0; k < 4; ++k) {
        int i = base + k;
        if (i < NN) { rs[i] = ex; ex += v[k]; if (i == NN - 1) rs[NN] = ex; }
    }
}

// ---------------- bin edges into CSR: partition = blockIdx%8 (XCD-owned ranges) ----------------

__global__ __launch_bounds__(256) void k_bin_x(const int* __restrict__ src,
                                               const int* __restrict__ dst,
                                               const int* __restrict__ rs,
                                               int* __restrict__ cursor,
                                               int* __restrict__ csr) {
    constexpr int NXCD = 8;
    constexpr int RANGE = (NN + NXCD - 1) / NXCD;   // 12500
    int part = blockIdx.x & (NXCD - 1);
    int lo = part * RANGE;
    int hi = min(lo + RANGE, NN);
    int bid = blockIdx.x >> 3;                      // block index within partition
    int nbp = gridDim.x >> 3;                       // blocks per partition
    int tid = bid * blockDim.x + threadIdx.x;
    int stride = nbp * blockDim.x;
    for (int e = tid; e < NE; e += stride) {
        int d = dst[e];
        if (d >= lo && d < hi) {
            int p = atomicAdd(&cursor[d], 1);
            csr[rs[d] + p] = src[e];
        }
    }
}

// ---------------- layer 1 GEMM: ht1 = bf16( (x @ W1) * dinv ) ----------------

__global__ __launch_bounds__(256) void k_gemm1(const float* __restrict__ x,
                                               const float* __restrict__ W1,
                                               const float* __restrict__ dinv,
                                               unsigned short* __restrict__ ht1) {
    __shared__ float w[64 * 64];
    for (int t = threadIdx.x; t < 64 * 64; t += 256) w[t] = W1[t];
    __syncthreads();

    int i = blockIdx.x * 256 + threadIdx.x;
    if (i >= NN) return;

    float xr[64];
    const float4* xp = reinterpret_cast<const float4*>(x + (size_t)i * 64);
    #pragma unroll
    for (int q = 0; q < 16; ++q) {
        float4 v = xp[q];
        xr[4 * q + 0] = v.x; xr[4 * q + 1] = v.y;
        xr[4 * q + 2] = v.z; xr[4 * q + 3] = v.w;
    }

    float acc[64];
    #pragma unroll
    for (int f = 0; f < 64; ++f) acc[f] = 0.f;

    for (int k = 0; k < 64; ++k) {
        float xk = xr[k];
        const float4* wr = reinterpret_cast<const float4*>(w + k * 64);
        #pragma unroll
        for (int f4 = 0; f4 < 16; ++f4) {
            float4 wv = wr[f4];
            acc[4 * f4 + 0] += xk * wv.x;
            acc[4 * f4 + 1] += xk * wv.y;
            acc[4 * f4 + 2] += xk * wv.z;
            acc[4 * f4 + 3] += xk * wv.w;
        }
    }

    float di = dinv[i];
    uint4* hp = reinterpret_cast<uint4*>(ht1 + (size_t)i * 64);
    #pragma unroll
    for (int q = 0; q < 8; ++q) {
        uint4 v;
        v.x = pack2(acc[8 * q + 0] * di, acc[8 * q + 1] * di);
        v.y = pack2(acc[8 * q + 2] * di, acc[8 * q + 3] * di);
        v.z = pack2(acc[8 * q + 4] * di, acc[8 * q + 5] * di);
        v.w = pack2(acc[8 * q + 6] * di, acc[8 * q + 7] * di);
        hp[q] = v;
    }
}

// ---------------- layer 1 gather: wave/node, 8 slots x 8 feat-groups (uint4) ----------------

__global__ __launch_bounds__(256) void k_gather1(const unsigned short* __restrict__ ht,
                                                 const int* __restrict__ rs,
                                                 const int* __restrict__ csr,
                                                 const float* __restrict__ dinv,
                                                 const float* __restrict__ b1,
                                                 float* __restrict__ h) {
    int wid = (blockIdx.x * 256 + threadIdx.x) >> 6;
    if (wid >= NN) return;
    int lane = threadIdx.x & 63;
    int q = lane >> 3;     // neighbor slot 0..7
    int g = lane & 7;      // feats 8g..8g+7
    int beg = rs[wid], end = rs[wid + 1];

    float a0 = 0.f, a1 = 0.f, a2 = 0.f, a3 = 0.f;
    float a4 = 0.f, a5 = 0.f, a6 = 0.f, a7 = 0.f;
    int j = beg + q;
    for (; j + 8 < end; j += 16) {
        int s  = csr[j];
        int s2 = csr[j + 8];
        uint4 w  = *reinterpret_cast<const uint4*>(ht + (size_t)s  * 64 + 8 * g);
        uint4 w2 = *reinterpret_cast<const uint4*>(ht + (size_t)s2 * 64 + 8 * g);
        a0 += bflo(w.x) + bflo(w2.x); a1 += bfhi(w.x) + bfhi(w2.x);
        a2 += bflo(w.y) + bflo(w2.y); a3 += bfhi(w.y) + bfhi(w2.y);
        a4 += bflo(w.z) + bflo(w2.z); a5 += bfhi(w.z) + bfhi(w2.z);
        a6 += bflo(w.w) + bflo(w2.w); a7 += bfhi(w.w) + bfhi(w2.w);
    }
    for (; j < end; j += 8) {
        int s = csr[j];
        uint4 w = *reinterpret_cast<const uint4*>(ht + (size_t)s * 64 + 8 * g);
        a0 += bflo(w.x); a1 += bfhi(w.x); a2 += bflo(w.y); a3 += bfhi(w.y);
        a4 += bflo(w.z); a5 += bfhi(w.z); a6 += bflo(w.w); a7 += bfhi(w.w);
    }

    #pragma unroll
    for (int off = 8; off < 64; off <<= 1) {
        a0 += __shfl_xor(a0, off); a1 += __shfl_xor(a1, off);
        a2 += __shfl_xor(a2, off); a3 += __shfl_xor(a3, off);
        a4 += __shfl_xor(a4, off); a5 += __shfl_xor(a5, off);
        a6 += __shfl_xor(a6, off); a7 += __shfl_xor(a7, off);
    }

    if (q == 0) {
        uint4 sw = *reinterpret_cast<const uint4*>(ht + (size_t)wid * 64 + 8 * g);
        a0 += bflo(sw.x); a1 += bfhi(sw.x); a2 += bflo(sw.y); a3 += bfhi(sw.y);
        a4 += bflo(sw.z); a5 += bfhi(sw.z); a6 += bflo(sw.w); a7 += bfhi(sw.w);
        float di = dinv[wid];
        const float4* bp = reinterpret_cast<const float4*>(b1 + 8 * g);
        float4 bA = bp[0], bB = bp[1];
        float4 vA, vB;
        vA.x = fmaxf(di * a0 + bA.x, 0.f); vA.y = fmaxf(di * a1 + bA.y, 0.f);
        vA.z = fmaxf(di * a2 + bA.z, 0.f); vA.w = fmaxf(di * a3 + bA.w, 0.f);
        vB.x = fmaxf(di * a4 + bB.x, 0.f); vB.y = fmaxf(di * a5 + bB.y, 0.f);
        vB.z = fmaxf(di * a6 + bB.z, 0.f); vB.w = fmaxf(di * a7 + bB.w, 0.f);
        float4* hp = reinterpret_cast<float4*>(h + (size_t)wid * 64 + 8 * g);
        hp[0] = vA; hp[1] = vB;
    }
}

// ---------------- layer 2 GEMM: htp = bf16((h@W2)[:, :32]*dinv), htm = f32 col 32 ----------------

__global__ __launch_bounds__(256) void k_gemm2(const float* __restrict__ h,
                                               const float* __restrict__ W2,
                                               const float* __restrict__ dinv,
                                               unsigned short* __restrict__ htp,
                                               float* __restrict__ htm) {
    __shared__ float w[64 * 36];   // padded stride 36 for float4 alignment
    for (int t = threadIdx.x; t < 64 * 36; t += 256) {
        int k = t / 36, c = t - k * 36;
        w[t] = (c < D2) ? W2[k * D2 + c] : 0.f;
    }
    __syncthreads();

    int i = blockIdx.x * 256 + threadIdx.x;
    if (i >= NN) return;

    float xr[64];
    const float4* xp = reinterpret_cast<const float4*>(h + (size_t)i * 64);
    #pragma unroll
    for (int q = 0; q < 16; ++q) {
        float4 v = xp[q];
        xr[4 * q + 0] = v.x; xr[4 * q + 1] = v.y;
        xr[4 * q + 2] = v.z; xr[4 * q + 3] = v.w;
    }

    float acc[36];
    #pragma unroll
    for (int c = 0; c < 36; ++c) acc[c] = 0.f;

    for (int k = 0; k < 64; ++k) {
        float xk = xr[k];
        const float4* wr = reinterpret_cast<const float4*>(w + k * 36);
        #pragma unroll
        for (int c4 = 0; c4 < 9; ++c4) {
            float4 wv = wr[c4];
            acc[4 * c4 + 0] += xk * wv.x;
            acc[4 * c4 + 1] += xk * wv.y;
            acc[4 * c4 + 2] += xk * wv.z;
            acc[4 * c4 + 3] += xk * wv.w;
        }
    }

    float di = dinv[i];
    uint4* pp = reinterpret_cast<uint4*>(htp + (size_t)i * 32);
    #pragma unroll
    for (int q = 0; q < 4; ++q) {
        uint4 v;
        v.x = pack2(acc[8 * q + 0] * di, acc[8 * q + 1] * di);
        v.y = pack2(acc[8 * q + 2] * di, acc[8 * q + 3] * di);
        v.z = pack2(acc[8 * q + 4] * di, acc[8 * q + 5] * di);
        v.w = pack2(acc[8 * q + 6] * di, acc[8 * q + 7] * di);
        pp[q] = v;
    }
    htm[i] = acc[32] * di;
}

// ---------------- layer 2 gather (+ epilogue): 8 slots x 8 feat-groups (uint2) + mass ----------------

__global__ __launch_bounds__(256) void k_gather2(const unsigned short* __restrict__ htp,
                                                 const float* __restrict__ htm,
                                                 const int* __restrict__ rs,
                                                 const int* __restrict__ csr,
                                                 const float* __restrict__ dinv,
                                                 const float* __restrict__ b2,
                                                 float* __restrict__ out) {
    int wid = (blockIdx.x * 256 + threadIdx.x) >> 6;
    if (wid >= NN) return;
    int lane = threadIdx.x & 63;
    int q = lane >> 3;     // neighbor slot 0..7
    int g = lane & 7;      // feats 4g..4g+3
    int beg = rs[wid], end = rs[wid + 1];

    float a0 = 0.f, a1 = 0.f, a2 = 0.f, a3 = 0.f;
    int j = beg + q;
    for (; j + 8 < end; j += 16) {
        int s  = csr[j];
        int s2 = csr[j + 8];
        uint2 w  = *reinterpret_cast<const uint2*>(htp + (size_t)s  * 32 + 4 * g);
        uint2 w2 = *reinterpret_cast<const uint2*>(htp + (size_t)s2 * 32 + 4 * g);
        a0 += bflo(w.x) + bflo(w2.x); a1 += bfhi(w.x) + bfhi(w2.x);
        a2 += bflo(w.y) + bflo(w2.y); a3 += bfhi(w.y) + bfhi(w2.y);
    }
    for (; j < end; j += 8) {
        int s = csr[j];
        uint2 w = *reinterpret_cast<const uint2*>(htp + (size_t)s * 32 + 4 * g);
        a0 += bflo(w.x); a1 += bfhi(w.x); a2 += bflo(w.y); a3 += bfhi(w.y);
    }

    // mass column: per-lane strided, f32 table
    float m = 0.f;
    for (int jm = beg + lane; jm < end; jm += 64) m += htm[csr[jm]];

    #pragma unroll
    for (int off = 8; off < 64; off <<= 1) {
        a0 += __shfl_xor(a0, off); a1 += __shfl_xor(a1, off);
        a2 += __shfl_xor(a2, off); a3 += __shfl_xor(a3, off);
    }
    m += __shfl_xor(m, 1);  m += __shfl_xor(m, 2);  m += __shfl_xor(m, 4);
    m += __shfl_xor(m, 8);  m += __shfl_xor(m, 16); m += __shfl_xor(m, 32);

    float di = dinv[wid];
    if (q == 0) {
        uint2 sw = *reinterpret_cast<const uint2*>(htp + (size_t)wid * 32 + 4 * g);
        a0 += bflo(sw.x); a1 += bfhi(sw.x); a2 += bflo(sw.y); a3 += bfhi(sw.y);
        const float4* bp = reinterpret_cast<const float4*>(b2 + 4 * g);
        float4 bv = bp[0];
        float4 v;
        v.x = di * a0 + bv.x; v.y = di * a1 + bv.y;
        v.z = di * a2 + bv.z; v.w = di * a3 + bv.w;
        *reinterpret_cast<float4*>(out + (size_t)wid * 32 + 4 * g) = v;
    }
    if (lane == 0) {
        float v = di * (m + htm[wid]) + b2[32];
        out[(size_t)NN * 32 + wid] = expf(v);
    }
}

extern "C" void kernel_launch(void* const* d_in, const int* in_sizes, int n_in,
                              void* d_out, int out_size, void* d_ws, size_t ws_size,
                              hipStream_t stream) {
    const float* x  = (const float*)d_in[0];
    const float* W1 = (const float*)d_in[1];
    const float* b1 = (const float*)d_in[2];
    const float* W2 = (const float*)d_in[3];
    const float* b2 = (const float*)d_in[4];
    const int*   ei = (const int*)d_in[5];
    const int* src = ei;
    const int* dst = ei + NE;
    float* out = (float*)d_out;

    // workspace layout
    char* p = (char*)d_ws;
    int* cnt    = (int*)p;              p += sizeof(int) * NN;
    int* rs     = (int*)p;              p += sizeof(int) * (NN + 1);
    int* cursor = (int*)p;              p += sizeof(int) * NN;
    int* bsum   = (int*)p;              p += sizeof(int) * NB;
    int* boff   = (int*)p;              p += sizeof(int) * NB;
    p = (char*)(((uintptr_t)p + 255) & ~(uintptr_t)255);
    int* csr    = (int*)p;              p += sizeof(int) * NE;
    p = (char*)(((uintptr_t)p + 255) & ~(uintptr_t)255);
    float* dinv = (float*)p;            p += sizeof(float) * NN;
    p = (char*)(((uintptr_t)p + 255) & ~(uintptr_t)255);
    unsigned short* ht1 = (unsigned short*)p; p += sizeof(unsigned short) * (size_t)NN * 64;
    p = (char*)(((uintptr_t)p + 255) & ~(uintptr_t)255);
    float* h    = (float*)p;            p += sizeof(float) * (size_t)NN * 64;
    p = (char*)(((uintptr_t)p + 255) & ~(uintptr_t)255);
    unsigned short* htp = (unsigned short*)p; p += sizeof(unsigned short) * (size_t)NN * 32;
    p = (char*)(((uintptr_t)p + 255) & ~(uintptr_t)255);
    float* htm  = (float*)p;            p += sizeof(float) * NN;

    // ---- CSR build ----
    hipMemsetAsync(cnt, 0, sizeof(int) * NN, stream);
    hipMemsetAsync(cursor, 0, sizeof(int) * NN, stream);
    k_cnt<<<(NE + 255) / 256, 256, 0, stream>>>(dst, cnt);
    k_dinv<<<(NN + 255) / 256, 256, 0, stream>>>(cnt, dinv);
    k_blocksum<<<NB, 256, 0, stream>>>(cnt, bsum);
    k_scanbsum<<<1, 128, 0, stream>>>(bsum, boff);
    k_scanfinal<<<NB, 256, 0, stream>>>(cnt, boff, rs);
    k_bin_x<<<2048, 256, 0, stream>>>(src, dst, rs, cursor, csr);

    // ---- layer 1 ----
    k_gemm1<<<(NN + 255) / 256, 256, 0, stream>>>(x, W1, dinv, ht1);
    k_gather1<<<(NN * 64 + 255) / 256, 256, 0, stream>>>(ht1, rs, csr, dinv, b1, h);

    // ---- layer 2 ----
    k_gemm2<<<(NN + 255) / 256, 256, 0, stream>>>(h, W2, dinv, htp, htm);
    k_gather2<<<(NN * 64 + 255) / 256, 256, 0, stream>>>(htp, htm, rs, csr, dinv, b2, out);
}

// Round 6
// 292.504 us; speedup vs baseline: 2.8826x; 1.1379x over previous
//
#include <hip/hip_runtime.h>
#include <hip/hip_bf16.h>

// GCN 2-layer: N=100000 nodes, E=1600000 edges, 64 -> 64(relu) -> 33.
// out = [pos (N*32) | mass (N*1)], float32.
//
// ht[i] = (x@W)[i] * dinv[i]
// gcnconv(x)[i] = dinv[i] * ( sum_{e: dst=i} ht[src[e]] + ht[i] ) + b
//
// R6: binning -> 2-pass LDS-staged multisplit.
//   pass1 k_split: coarse 196-way split by dst>>9, tile-staged in LDS, flushed
//     as bucket-grouped contiguous segments (write lines = cursor fronts only).
//   pass2 k_bin2: block-per-bucket fine binning; each 32KB csr region written
//     by ONE CU within one block lifetime via LDS cursors -> full-line writebacks.
// (R4/R5 lesson: scattered 4B stores spread over the kernel lifetime get
// evicted part-full regardless of XCD ownership; cluster them in TIME.)

constexpr int NN = 100000;
constexpr int NE = 1600000;
constexpr int D2 = 33;   // OUT + 1

constexpr int SCAN_CHUNK = 1024;                       // 256 thr x 4 items
constexpr int NB = (NN + SCAN_CHUNK - 1) / SCAN_CHUNK; // 98 (<=128)

constexpr int BSHIFT = 9;                              // 512 nodes per bucket
constexpr int NBUCK = (NN + (1 << BSHIFT) - 1) >> BSHIFT;  // 196
constexpr int TILE = 4096;                             // edges per split tile
constexpr int NTILE = (NE + TILE - 1) / TILE;          // 391

// ---------------- bf16 helpers ----------------

__device__ inline float bflo(unsigned w) { union { unsigned u; float f; } c; c.u = w << 16; return c.f; }
__device__ inline float bfhi(unsigned w) { union { unsigned u; float f; } c; c.u = w & 0xffff0000u; return c.f; }
__device__ inline unsigned f2bf_bits(float f) {
    __hip_bfloat16 h = __float2bfloat16(f);
    unsigned short u; __builtin_memcpy(&u, &h, 2); return (unsigned)u;
}
__device__ inline unsigned pack2(float a, float b) { return f2bf_bits(a) | (f2bf_bits(b) << 16); }

// ---------------- degree count (int) ----------------

__global__ void k_cnt(const int* __restrict__ dst, int* __restrict__ cnt) {
    int e = blockIdx.x * blockDim.x + threadIdx.x;
    if (e < NE) atomicAdd(&cnt[dst[e]], 1);
}

__global__ void k_dinv(const int* __restrict__ cnt, float* __restrict__ dinv) {
    int i = blockIdx.x * blockDim.x + threadIdx.x;
    if (i < NN) dinv[i] = rsqrtf((float)cnt[i] + 1.0f);
}

// ---------------- exclusive scan of cnt -> rs[0..NN] ----------------

__global__ void k_blocksum(const int* __restrict__ cnt, int* __restrict__ bsum) {
    __shared__ int sh[256];
    int base = blockIdx.x * SCAN_CHUNK + threadIdx.x * 4;
    int s = 0;
    #pragma unroll
    for (int k = 0; k < 4; ++k) { int i = base + k; if (i < NN) s += cnt[i]; }
    sh[threadIdx.x] = s; __syncthreads();
    for (int off = 128; off > 0; off >>= 1) {
        if (threadIdx.x < off) sh[threadIdx.x] += sh[threadIdx.x + off];
        __syncthreads();
    }
    if (threadIdx.x == 0) bsum[blockIdx.x] = sh[0];
}

__global__ void k_scanbsum(const int* __restrict__ bsum, int* __restrict__ boff) {
    __shared__ int sh[128];
    int t = threadIdx.x;
    int v = (t < NB) ? bsum[t] : 0;
    sh[t] = v; __syncthreads();
    for (int off = 1; off < 128; off <<= 1) {
        int add = (t >= off) ? sh[t - off] : 0;
        __syncthreads();
        sh[t] += add;
        __syncthreads();
    }
    if (t < NB) boff[t] = sh[t] - v;   // exclusive
}

__global__ void k_scanfinal(const int* __restrict__ cnt, const int* __restrict__ boff,
                            int* __restrict__ rs) {
    __shared__ int sh[256];
    int t = threadIdx.x;
    int base = blockIdx.x * SCAN_CHUNK + t * 4;
    int v[4]; int s = 0;
    #pragma unroll
    for (int k = 0; k < 4; ++k) { int i = base + k; v[k] = (i < NN) ? cnt[i] : 0; s += v[k]; }
    sh[t] = s; __syncthreads();
    for (int off = 1; off < 256; off <<= 1) {
        int add = (t >= off) ? sh[t - off] : 0;
        __syncthreads();
        sh[t] += add;
        __syncthreads();
    }
    int ex = sh[t] - s + boff[blockIdx.x];
    #pragma unroll
    for (int k = 0; k < 4; ++k) {
        int i = base + k;
        if (i < NN) { rs[i] = ex; ex += v[k]; if (i == NN - 1) rs[NN] = ex; }
    }
}

// ---------------- pass-1 init: bucket cursors start at rs[b<<9] ----------------

__global__ void k_initgcur(const int* __restrict__ rs, int* __restrict__ gcur) {
    int t = threadIdx.x;
    if (t < NBUCK) gcur[t] = rs[t << BSHIFT];
}

// ---------------- pass 1: 196-way LDS-staged split, pairs[e] = src | dloc<<17 ----------------

__global__ __launch_bounds__(256) void k_split(const int* __restrict__ src,
                                               const int* __restrict__ dst,
                                               int* __restrict__ gcur,
                                               unsigned* __restrict__ pairs) {
    __shared__ int lcnt[256];
    __shared__ int lpre[256];
    __shared__ int gadj[NBUCK];
    __shared__ unsigned buf[TILE];       // 16 KB
    __shared__ unsigned char bb[TILE];   // 4 KB
    int tid = threadIdx.x;
    int base = blockIdx.x * TILE;

    lcnt[tid] = 0;
    __syncthreads();

    unsigned pk[16]; short bk[16]; short lp[16];
    #pragma unroll
    for (int k = 0; k < 16; ++k) {
        int e = base + k * 256 + tid;
        bk[k] = -1;
        if (e < NE) {
            int s = src[e], d = dst[e];
            int b = d >> BSHIFT;
            pk[k] = (unsigned)s | ((unsigned)(d & ((1 << BSHIFT) - 1)) << 17);
            bk[k] = (short)b;
            lp[k] = (short)atomicAdd(&lcnt[b], 1);
        }
    }
    __syncthreads();

    // Hillis-Steele inclusive scan over 256 (lcnt -> lpre)
    lpre[tid] = lcnt[tid];
    __syncthreads();
    for (int off = 1; off < 256; off <<= 1) {
        int v = (tid >= off) ? lpre[tid - off] : 0;
        __syncthreads();
        lpre[tid] += v;
        __syncthreads();
    }
    int total = lpre[255];

    // reserve global ranges; gadj[b] folds gbase - exclusive_prefix
    if (tid < NBUCK) {
        int ex = lpre[tid] - lcnt[tid];
        gadj[tid] = atomicAdd(&gcur[tid], lcnt[tid]) - ex;
    }
    __syncthreads();

    // stage bucket-grouped into LDS
    #pragma unroll
    for (int k = 0; k < 16; ++k) {
        if (bk[k] >= 0) {
            int b = bk[k];
            int i = (lpre[b] - lcnt[b]) + lp[k];
            buf[i] = pk[k];
            bb[i] = (unsigned char)b;
        }
    }
    __syncthreads();

    // flush: contiguous per-bucket segments
    for (int i = tid; i < total; i += 256) {
        pairs[gadj[bb[i]] + i] = buf[i];
    }
}

// ---------------- pass 2: block-per-bucket fine binning via LDS cursors ----------------

__global__ __launch_bounds__(256) void k_bin2(const unsigned* __restrict__ pairs,
                                              const int* __restrict__ rs,
                                              int* __restrict__ csr) {
    int b = blockIdx.x;
    int lo = b << BSHIFT;
    int nn = min(1 << BSHIFT, NN - lo);
    __shared__ int rsl[(1 << BSHIFT) + 1];
    __shared__ int cur[1 << BSHIFT];
    for (int i = threadIdx.x; i < nn; i += 256) { rsl[i] = rs[lo + i]; cur[i] = 0; }
    if (threadIdx.x == 0) rsl[nn] = rs[lo + nn];
    __syncthreads();
    int beg = rsl[0], endd = rsl[nn];
    for (int idx = beg + threadIdx.x; idx < endd; idx += 256) {
        unsigned v = pairs[idx];
        int s = (int)(v & 0x1FFFFu);
        int dl = (int)(v >> 17);
        int p = atomicAdd(&cur[dl], 1);
        csr[rsl[dl] + p] = s;
    }
}

// ---------------- layer 1 GEMM: ht1 = bf16( (x @ W1) * dinv ) ----------------

__global__ __launch_bounds__(256) void k_gemm1(const float* __restrict__ x,
                                               const float* __restrict__ W1,
                                               const float* __restrict__ dinv,
                                               unsigned short* __restrict__ ht1) {
    __shared__ float w[64 * 64];
    for (int t = threadIdx.x; t < 64 * 64; t += 256) w[t] = W1[t];
    __syncthreads();

    int i = blockIdx.x * 256 + threadIdx.x;
    if (i >= NN) return;

    float xr[64];
    const float4* xp = reinterpret_cast<const float4*>(x + (size_t)i * 64);
    #pragma unroll
    for (int q = 0; q < 16; ++q) {
        float4 v = xp[q];
        xr[4 * q + 0] = v.x; xr[4 * q + 1] = v.y;
        xr[4 * q + 2] = v.z; xr[4 * q + 3] = v.w;
    }

    float acc[64];
    #pragma unroll
    for (int f = 0; f < 64; ++f) acc[f] = 0.f;

    for (int k = 0; k < 64; ++k) {
        float xk = xr[k];
        const float4* wr = reinterpret_cast<const float4*>(w + k * 64);
        #pragma unroll
        for (int f4 = 0; f4 < 16; ++f4) {
            float4 wv = wr[f4];
            acc[4 * f4 + 0] += xk * wv.x;
            acc[4 * f4 + 1] += xk * wv.y;
            acc[4 * f4 + 2] += xk * wv.z;
            acc[4 * f4 + 3] += xk * wv.w;
        }
    }

    float di = dinv[i];
    uint4* hp = reinterpret_cast<uint4*>(ht1 + (size_t)i * 64);
    #pragma unroll
    for (int q = 0; q < 8; ++q) {
        uint4 v;
        v.x = pack2(acc[8 * q + 0] * di, acc[8 * q + 1] * di);
        v.y = pack2(acc[8 * q + 2] * di, acc[8 * q + 3] * di);
        v.z = pack2(acc[8 * q + 4] * di, acc[8 * q + 5] * di);
        v.w = pack2(acc[8 * q + 6] * di, acc[8 * q + 7] * di);
        hp[q] = v;
    }
}

// ---------------- layer 1 gather: wave/node, 8 slots x 8 feat-groups (uint4) ----------------

__global__ __launch_bounds__(256) void k_gather1(const unsigned short* __restrict__ ht,
                                                 const int* __restrict__ rs,
                                                 const int* __restrict__ csr,
                                                 const float* __restrict__ dinv,
                                                 const float* __restrict__ b1,
                                                 float* __restrict__ h) {
    int wid = (blockIdx.x * 256 + threadIdx.x) >> 6;
    if (wid >= NN) return;
    int lane = threadIdx.x & 63;
    int q = lane >> 3;     // neighbor slot 0..7
    int g = lane & 7;      // feats 8g..8g+7
    int beg = rs[wid], end = rs[wid + 1];

    float a0 = 0.f, a1 = 0.f, a2 = 0.f, a3 = 0.f;
    float a4 = 0.f, a5 = 0.f, a6 = 0.f, a7 = 0.f;
    int j = beg + q;
    for (; j + 8 < end; j += 16) {
        int s  = csr[j];
        int s2 = csr[j + 8];
        uint4 w  = *reinterpret_cast<const uint4*>(ht + (size_t)s  * 64 + 8 * g);
        uint4 w2 = *reinterpret_cast<const uint4*>(ht + (size_t)s2 * 64 + 8 * g);
        a0 += bflo(w.x) + bflo(w2.x); a1 += bfhi(w.x) + bfhi(w2.x);
        a2 += bflo(w.y) + bflo(w2.y); a3 += bfhi(w.y) + bfhi(w2.y);
        a4 += bflo(w.z) + bflo(w2.z); a5 += bfhi(w.z) + bfhi(w2.z);
        a6 += bflo(w.w) + bflo(w2.w); a7 += bfhi(w.w) + bfhi(w2.w);
    }
    for (; j < end; j += 8) {
        int s = csr[j];
        uint4 w = *reinterpret_cast<const uint4*>(ht + (size_t)s * 64 + 8 * g);
        a0 += bflo(w.x); a1 += bfhi(w.x); a2 += bflo(w.y); a3 += bfhi(w.y);
        a4 += bflo(w.z); a5 += bfhi(w.z); a6 += bflo(w.w); a7 += bfhi(w.w);
    }

    #pragma unroll
    for (int off = 8; off < 64; off <<= 1) {
        a0 += __shfl_xor(a0, off); a1 += __shfl_xor(a1, off);
        a2 += __shfl_xor(a2, off); a3 += __shfl_xor(a3, off);
        a4 += __shfl_xor(a4, off); a5 += __shfl_xor(a5, off);
        a6 += __shfl_xor(a6, off); a7 += __shfl_xor(a7, off);
    }

    if (q == 0) {
        uint4 sw = *reinterpret_cast<const uint4*>(ht + (size_t)wid * 64 + 8 * g);
        a0 += bflo(sw.x); a1 += bfhi(sw.x); a2 += bflo(sw.y); a3 += bfhi(sw.y);
        a4 += bflo(sw.z); a5 += bfhi(sw.z); a6 += bflo(sw.w); a7 += bfhi(sw.w);
        float di = dinv[wid];
        const float4* bp = reinterpret_cast<const float4*>(b1 + 8 * g);
        float4 bA = bp[0], bB = bp[1];
        float4 vA, vB;
        vA.x = fmaxf(di * a0 + bA.x, 0.f); vA.y = fmaxf(di * a1 + bA.y, 0.f);
        vA.z = fmaxf(di * a2 + bA.z, 0.f); vA.w = fmaxf(di * a3 + bA.w, 0.f);
        vB.x = fmaxf(di * a4 + bB.x, 0.f); vB.y = fmaxf(di * a5 + bB.y, 0.f);
        vB.z = fmaxf(di * a6 + bB.z, 0.f); vB.w = fmaxf(di * a7 + bB.w, 0.f);
        float4* hp = reinterpret_cast<float4*>(h + (size_t)wid * 64 + 8 * g);
        hp[0] = vA; hp[1] = vB;
    }
}

// ---------------- layer 2 GEMM: htp = bf16((h@W2)[:, :32]*dinv), htm = f32 col 32 ----------------

__global__ __launch_bounds__(256) void k_gemm2(const float* __restrict__ h,
                                               const float* __restrict__ W2,
                                               const float* __restrict__ dinv,
                                               unsigned short* __restrict__ htp,
                                               float* __restrict__ htm) {
    __shared__ float w[64 * 36];   // padded stride 36 for float4 alignment
    for (int t = threadIdx.x; t < 64 * 36; t += 256) {
        int k = t / 36, c = t - k * 36;
        w[t] = (c < D2) ? W2[k * D2 + c] : 0.f;
    }
    __syncthreads();

    int i = blockIdx.x * 256 + threadIdx.x;
    if (i >= NN) return;

    float xr[64];
    const float4* xp = reinterpret_cast<const float4*>(h + (size_t)i * 64);
    #pragma unroll
    for (int q = 0; q < 16; ++q) {
        float4 v = xp[q];
        xr[4 * q + 0] = v.x; xr[4 * q + 1] = v.y;
        xr[4 * q + 2] = v.z; xr[4 * q + 3] = v.w;
    }

    float acc[36];
    #pragma unroll
    for (int c = 0; c < 36; ++c) acc[c] = 0.f;

    for (int k = 0; k < 64; ++k) {
        float xk = xr[k];
        const float4* wr = reinterpret_cast<const float4*>(w + k * 36);
        #pragma unroll
        for (int c4 = 0; c4 < 9; ++c4) {
            float4 wv = wr[c4];
            acc[4 * c4 + 0] += xk * wv.x;
            acc[4 * c4 + 1] += xk * wv.y;
            acc[4 * c4 + 2] += xk * wv.z;
            acc[4 * c4 + 3] += xk * wv.w;
        }
    }

    float di = dinv[i];
    uint4* pp = reinterpret_cast<uint4*>(htp + (size_t)i * 32);
    #pragma unroll
    for (int q = 0; q < 4; ++q) {
        uint4 v;
        v.x = pack2(acc[8 * q + 0] * di, acc[8 * q + 1] * di);
        v.y = pack2(acc[8 * q + 2] * di, acc[8 * q + 3] * di);
        v.z = pack2(acc[8 * q + 4] * di, acc[8 * q + 5] * di);
        v.w = pack2(acc[8 * q + 6] * di, acc[8 * q + 7] * di);
        pp[q] = v;
    }
    htm[i] = acc[32] * di;
}

// ---------------- layer 2 gather (+ epilogue): 8 slots x 8 feat-groups (uint2) + mass ----------------

__global__ __launch_bounds__(256) void k_gather2(const unsigned short* __restrict__ htp,
                                                 const float* __restrict__ htm,
                                                 const int* __restrict__ rs,
                                                 const int* __restrict__ csr,
                                                 const float* __restrict__ dinv,
                                                 const float* __restrict__ b2,
                                                 float* __restrict__ out) {
    int wid = (blockIdx.x * 256 + threadIdx.x) >> 6;
    if (wid >= NN) return;
    int lane = threadIdx.x & 63;
    int q = lane >> 3;     // neighbor slot 0..7
    int g = lane & 7;      // feats 4g..4g+3
    int beg = rs[wid], end = rs[wid + 1];

    float a0 = 0.f, a1 = 0.f, a2 = 0.f, a3 = 0.f;
    int j = beg + q;
    for (; j + 8 < end; j += 16) {
        int s  = csr[j];
        int s2 = csr[j + 8];
        uint2 w  = *reinterpret_cast<const uint2*>(htp + (size_t)s  * 32 + 4 * g);
        uint2 w2 = *reinterpret_cast<const uint2*>(htp + (size_t)s2 * 32 + 4 * g);
        a0 += bflo(w.x) + bflo(w2.x); a1 += bfhi(w.x) + bfhi(w2.x);
        a2 += bflo(w.y) + bflo(w2.y); a3 += bfhi(w.y) + bfhi(w2.y);
    }
    for (; j < end; j += 8) {
        int s = csr[j];
        uint2 w = *reinterpret_cast<const uint2*>(htp + (size_t)s * 32 + 4 * g);
        a0 += bflo(w.x); a1 += bfhi(w.x); a2 += bflo(w.y); a3 += bfhi(w.y);
    }

    // mass column: per-lane strided, f32 table
    float m = 0.f;
    for (int jm = beg + lane; jm < end; jm += 64) m += htm[csr[jm]];

    #pragma unroll
    for (int off = 8; off < 64; off <<= 1) {
        a0 += __shfl_xor(a0, off); a1 += __shfl_xor(a1, off);
        a2 += __shfl_xor(a2, off); a3 += __shfl_xor(a3, off);
    }
    m += __shfl_xor(m, 1);  m += __shfl_xor(m, 2);  m += __shfl_xor(m, 4);
    m += __shfl_xor(m, 8);  m += __shfl_xor(m, 16); m += __shfl_xor(m, 32);

    float di = dinv[wid];
    if (q == 0) {
        uint2 sw = *reinterpret_cast<const uint2*>(htp + (size_t)wid * 32 + 4 * g);
        a0 += bflo(sw.x); a1 += bfhi(sw.x); a2 += bflo(sw.y); a3 += bfhi(sw.y);
        const float4* bp = reinterpret_cast<const float4*>(b2 + 4 * g);
        float4 bv = bp[0];
        float4 v;
        v.x = di * a0 + bv.x; v.y = di * a1 + bv.y;
        v.z = di * a2 + bv.z; v.w = di * a3 + bv.w;
        *reinterpret_cast<float4*>(out + (size_t)wid * 32 + 4 * g) = v;
    }
    if (lane == 0) {
        float v = di * (m + htm[wid]) + b2[32];
        out[(size_t)NN * 32 + wid] = expf(v);
    }
}

extern "C" void kernel_launch(void* const* d_in, const int* in_sizes, int n_in,
                              void* d_out, int out_size, void* d_ws, size_t ws_size,
                              hipStream_t stream) {
    const float* x  = (const float*)d_in[0];
    const float* W1 = (const float*)d_in[1];
    const float* b1 = (const float*)d_in[2];
    const float* W2 = (const float*)d_in[3];
    const float* b2 = (const float*)d_in[4];
    const int*   ei = (const int*)d_in[5];
    const int* src = ei;
    const int* dst = ei + NE;
    float* out = (float*)d_out;

    // workspace layout
    char* p = (char*)d_ws;
    int* cnt    = (int*)p;              p += sizeof(int) * NN;
    int* rs     = (int*)p;              p += sizeof(int) * (NN + 1);
    int* gcur   = (int*)p;              p += sizeof(int) * NBUCK;
    int* bsum   = (int*)p;              p += sizeof(int) * NB;
    int* boff   = (int*)p;              p += sizeof(int) * NB;
    p = (char*)(((uintptr_t)p + 255) & ~(uintptr_t)255);
    int* csr    = (int*)p;              p += sizeof(int) * NE;
    p = (char*)(((uintptr_t)p + 255) & ~(uintptr_t)255);
    unsigned* pairs = (unsigned*)p;     p += sizeof(unsigned) * NE;
    p = (char*)(((uintptr_t)p + 255) & ~(uintptr_t)255);
    float* dinv = (float*)p;            p += sizeof(float) * NN;
    p = (char*)(((uintptr_t)p + 255) & ~(uintptr_t)255);
    unsigned short* ht1 = (unsigned short*)p; p += sizeof(unsigned short) * (size_t)NN * 64;
    p = (char*)(((uintptr_t)p + 255) & ~(uintptr_t)255);
    float* h    = (float*)p;            p += sizeof(float) * (size_t)NN * 64;
    p = (char*)(((uintptr_t)p + 255) & ~(uintptr_t)255);
    unsigned short* htp = (unsigned short*)p; p += sizeof(unsigned short) * (size_t)NN * 32;
    p = (char*)(((uintptr_t)p + 255) & ~(uintptr_t)255);
    float* htm  = (float*)p;            p += sizeof(float) * NN;

    // ---- CSR build ----
    hipMemsetAsync(cnt, 0, sizeof(int) * NN, stream);
    k_cnt<<<(NE + 255) / 256, 256, 0, stream>>>(dst, cnt);
    k_dinv<<<(NN + 255) / 256, 256, 0, stream>>>(cnt, dinv);
    k_blocksum<<<NB, 256, 0, stream>>>(cnt, bsum);
    k_scanbsum<<<1, 128, 0, stream>>>(bsum, boff);
    k_scanfinal<<<NB, 256, 0, stream>>>(cnt, boff, rs);
    k_initgcur<<<1, 256, 0, stream>>>(rs, gcur);
    k_split<<<NTILE, 256, 0, stream>>>(src, dst, gcur, pairs);
    k_bin2<<<NBUCK, 256, 0, stream>>>(pairs, rs, csr);

    // ---- layer 1 ----
    k_gemm1<<<(NN + 255) / 256, 256, 0, stream>>>(x, W1, dinv, ht1);
    k_gather1<<<(NN * 64 + 255) / 256, 256, 0, stream>>>(ht1, rs, csr, dinv, b1, h);

    // ---- layer 2 ----
    k_gemm2<<<(NN + 255) / 256, 256, 0, stream>>>(h, W2, dinv, htp, htm);
    k_gather2<<<(NN * 64 + 255) / 256, 256, 0, stream>>>(htp, htm, rs, csr, dinv, b2, out);
}

// Round 7
// 221.094 us; speedup vs baseline: 3.8136x; 1.3230x over previous
//
#include <hip/hip_runtime.h>
#include <hip/hip_bf16.h>

// GCN 2-layer: N=100000 nodes, E=1600000 edges, 64 -> 64(relu) -> 33.
// out = [pos (N*32) | mass (N*1)], float32.
//
// ht[i] = (x@W)[i] * dinv[i]
// gcnconv(x)[i] = dinv[i] * ( sum_{e: dst=i} ht[src[e]] + ht[i] ) + b
//
// R7: (a) fix k_gemm* scratch spill (VGPR_Count=56 vs ~130 live floats:
// __launch_bounds__(256,1) + chunked x staging); (b) remove k_cnt (65us of
// 32B-sector atomic write-through) + scan kernels: counts/rs/dinv are now
// byproducts of the multisplit (k_hist LDS histogram -> k_scanb bucket scan
// -> k_split -> k_bin2 computes per-node counts, rs, dinv, csr in LDS).

constexpr int NN = 100000;
constexpr int NE = 1600000;
constexpr int D2 = 33;   // OUT + 1

constexpr int BSHIFT = 9;                              // 512 nodes per bucket
constexpr int NBUCK = (NN + (1 << BSHIFT) - 1) >> BSHIFT;  // 196
constexpr int TILE = 4096;                             // edges per split tile
constexpr int NTILE = (NE + TILE - 1) / TILE;          // 391

// ---------------- bf16 helpers ----------------

__device__ inline float bflo(unsigned w) { union { unsigned u; float f; } c; c.u = w << 16; return c.f; }
__device__ inline float bfhi(unsigned w) { union { unsigned u; float f; } c; c.u = w & 0xffff0000u; return c.f; }
__device__ inline unsigned f2bf_bits(float f) {
    __hip_bfloat16 h = __float2bfloat16(f);
    unsigned short u; __builtin_memcpy(&u, &h, 2); return (unsigned)u;
}
__device__ inline unsigned pack2(float a, float b) { return f2bf_bits(a) | (f2bf_bits(b) << 16); }

// ---------------- pass 0: bucket histogram (dst>>9) via LDS ----------------

__global__ __launch_bounds__(256) void k_hist(const int* __restrict__ dst,
                                              int* __restrict__ gbcnt) {
    __shared__ int hc[NBUCK];
    for (int i = threadIdx.x; i < NBUCK; i += 256) hc[i] = 0;
    __syncthreads();
    int base = blockIdx.x * TILE;
    #pragma unroll
    for (int k = 0; k < 16; ++k) {
        int e = base + k * 256 + threadIdx.x;
        if (e < NE) atomicAdd(&hc[dst[e] >> BSHIFT], 1);
    }
    __syncthreads();
    for (int i = threadIdx.x; i < NBUCK; i += 256)
        if (hc[i]) atomicAdd(&gbcnt[i], hc[i]);
}

// ---------------- scan bucket counts -> bbase[0..NBUCK], gcur; rs[NN]=NE ----------------

__global__ void k_scanb(const int* __restrict__ gbcnt, int* __restrict__ bbase,
                        int* __restrict__ gcur, int* __restrict__ rs) {
    __shared__ int sh[256];
    int t = threadIdx.x;
    int v = (t < NBUCK) ? gbcnt[t] : 0;
    sh[t] = v; __syncthreads();
    for (int off = 1; off < 256; off <<= 1) {
        int a = (t >= off) ? sh[t - off] : 0;
        __syncthreads();
        sh[t] += a;
        __syncthreads();
    }
    if (t < NBUCK) { int ex = sh[t] - v; bbase[t] = ex; gcur[t] = ex; }
    if (t == NBUCK - 1) bbase[NBUCK] = sh[t];
    if (t == 0) rs[NN] = NE;
}

// ---------------- pass 1: 196-way LDS-staged split, pairs[e] = src | dloc<<17 ----------------

__global__ __launch_bounds__(256) void k_split(const int* __restrict__ src,
                                               const int* __restrict__ dst,
                                               int* __restrict__ gcur,
                                               unsigned* __restrict__ pairs) {
    __shared__ int lcnt[256];
    __shared__ int lpre[256];
    __shared__ int gadj[NBUCK];
    __shared__ unsigned buf[TILE];       // 16 KB
    __shared__ unsigned char bb[TILE];   // 4 KB
    int tid = threadIdx.x;
    int base = blockIdx.x * TILE;

    lcnt[tid] = 0;
    __syncthreads();

    unsigned pk[16]; short bk[16]; short lp[16];
    #pragma unroll
    for (int k = 0; k < 16; ++k) {
        int e = base + k * 256 + tid;
        bk[k] = -1;
        if (e < NE) {
            int s = src[e], d = dst[e];
            int b = d >> BSHIFT;
            pk[k] = (unsigned)s | ((unsigned)(d & ((1 << BSHIFT) - 1)) << 17);
            bk[k] = (short)b;
            lp[k] = (short)atomicAdd(&lcnt[b], 1);
        }
    }
    __syncthreads();

    lpre[tid] = lcnt[tid];
    __syncthreads();
    for (int off = 1; off < 256; off <<= 1) {
        int v = (tid >= off) ? lpre[tid - off] : 0;
        __syncthreads();
        lpre[tid] += v;
        __syncthreads();
    }
    int total = lpre[255];

    if (tid < NBUCK) {
        int ex = lpre[tid] - lcnt[tid];
        gadj[tid] = atomicAdd(&gcur[tid], lcnt[tid]) - ex;
    }
    __syncthreads();

    #pragma unroll
    for (int k = 0; k < 16; ++k) {
        if (bk[k] >= 0) {
            int b = bk[k];
            int i = (lpre[b] - lcnt[b]) + lp[k];
            buf[i] = pk[k];
            bb[i] = (unsigned char)b;
        }
    }
    __syncthreads();

    for (int i = tid; i < total; i += 256) {
        pairs[gadj[bb[i]] + i] = buf[i];
    }
}

// ---------------- pass 2: block-per-bucket; emits csr, rs, dinv ----------------

__global__ __launch_bounds__(256) void k_bin2(const unsigned* __restrict__ pairs,
                                              const int* __restrict__ bbase,
                                              int* __restrict__ csr,
                                              int* __restrict__ rs,
                                              float* __restrict__ dinv) {
    int b = blockIdx.x;
    int lo = b << BSHIFT;
    int nn = min(1 << BSHIFT, NN - lo);
    int beg = bbase[b], endd = bbase[b + 1];
    int t = threadIdx.x;

    __shared__ int lcnt[1 << BSHIFT];
    __shared__ int loff[1 << BSHIFT];
    __shared__ int wsum[256];

    for (int i = t; i < (1 << BSHIFT); i += 256) lcnt[i] = 0;
    __syncthreads();
    for (int idx = beg + t; idx < endd; idx += 256)
        atomicAdd(&lcnt[pairs[idx] >> 17], 1);
    __syncthreads();

    // exclusive scan of lcnt[512]: thread t owns elements 2t, 2t+1
    int v0 = lcnt[2 * t], v1 = lcnt[2 * t + 1];
    int s = v0 + v1;
    wsum[t] = s; __syncthreads();
    for (int off = 1; off < 256; off <<= 1) {
        int a = (t >= off) ? wsum[t - off] : 0;
        __syncthreads();
        wsum[t] += a;
        __syncthreads();
    }
    int ex = wsum[t] - s;
    loff[2 * t] = ex; loff[2 * t + 1] = ex + v0;
    __syncthreads();

    for (int i = t; i < nn; i += 256) {
        rs[lo + i] = beg + loff[i];
        dinv[lo + i] = rsqrtf((float)lcnt[i] + 1.0f);
    }
    __syncthreads();
    for (int i = t; i < (1 << BSHIFT); i += 256) lcnt[i] = 0;  // reuse as cursors
    __syncthreads();

    for (int idx = beg + t; idx < endd; idx += 256) {
        unsigned v = pairs[idx];
        int dl = (int)(v >> 17);
        int p = atomicAdd(&lcnt[dl], 1);
        csr[beg + loff[dl] + p] = (int)(v & 0x1FFFFu);
    }
}

// ---------------- layer 1 GEMM: ht1 = bf16( (x @ W1) * dinv ) ----------------

__global__ __launch_bounds__(256, 1) void k_gemm1(const float* __restrict__ x,
                                                  const float* __restrict__ W1,
                                                  const float* __restrict__ dinv,
                                                  unsigned short* __restrict__ ht1) {
    __shared__ float w[64 * 64];
    for (int t = threadIdx.x; t < 64 * 64; t += 256) w[t] = W1[t];
    __syncthreads();

    int i = blockIdx.x * 256 + threadIdx.x;
    if (i >= NN) return;

    float acc[64];
    #pragma unroll
    for (int f = 0; f < 64; ++f) acc[f] = 0.f;

    const float4* xp = reinterpret_cast<const float4*>(x + (size_t)i * 64);
    #pragma unroll
    for (int kc = 0; kc < 4; ++kc) {
        float4 c0 = xp[4 * kc + 0], c1 = xp[4 * kc + 1];
        float4 c2 = xp[4 * kc + 2], c3 = xp[4 * kc + 3];
        float xs[16] = {c0.x, c0.y, c0.z, c0.w, c1.x, c1.y, c1.z, c1.w,
                        c2.x, c2.y, c2.z, c2.w, c3.x, c3.y, c3.z, c3.w};
        #pragma unroll
        for (int kk = 0; kk < 16; ++kk) {
            float xk = xs[kk];
            const float4* wr = reinterpret_cast<const float4*>(w + (16 * kc + kk) * 64);
            #pragma unroll
            for (int f4 = 0; f4 < 16; ++f4) {
                float4 wv = wr[f4];
                acc[4 * f4 + 0] += xk * wv.x;
                acc[4 * f4 + 1] += xk * wv.y;
                acc[4 * f4 + 2] += xk * wv.z;
                acc[4 * f4 + 3] += xk * wv.w;
            }
        }
    }

    float di = dinv[i];
    uint4* hp = reinterpret_cast<uint4*>(ht1 + (size_t)i * 64);
    #pragma unroll
    for (int q = 0; q < 8; ++q) {
        uint4 v;
        v.x = pack2(acc[8 * q + 0] * di, acc[8 * q + 1] * di);
        v.y = pack2(acc[8 * q + 2] * di, acc[8 * q + 3] * di);
        v.z = pack2(acc[8 * q + 4] * di, acc[8 * q + 5] * di);
        v.w = pack2(acc[8 * q + 6] * di, acc[8 * q + 7] * di);
        hp[q] = v;
    }
}

// ---------------- layer 1 gather: wave/node, 8 slots x 8 feat-groups (uint4) ----------------

__global__ __launch_bounds__(256) void k_gather1(const unsigned short* __restrict__ ht,
                                                 const int* __restrict__ rs,
                                                 const int* __restrict__ csr,
                                                 const float* __restrict__ dinv,
                                                 const float* __restrict__ b1,
                                                 float* __restrict__ h) {
    int wid = (blockIdx.x * 256 + threadIdx.x) >> 6;
    if (wid >= NN) return;
    int lane = threadIdx.x & 63;
    int q = lane >> 3;     // neighbor slot 0..7
    int g = lane & 7;      // feats 8g..8g+7
    int beg = rs[wid], end = rs[wid + 1];

    float a0 = 0.f, a1 = 0.f, a2 = 0.f, a3 = 0.f;
    float a4 = 0.f, a5 = 0.f, a6 = 0.f, a7 = 0.f;
    int j = beg + q;
    for (; j + 8 < end; j += 16) {
        int s  = csr[j];
        int s2 = csr[j + 8];
        uint4 w  = *reinterpret_cast<const uint4*>(ht + (size_t)s  * 64 + 8 * g);
        uint4 w2 = *reinterpret_cast<const uint4*>(ht + (size_t)s2 * 64 + 8 * g);
        a0 += bflo(w.x) + bflo(w2.x); a1 += bfhi(w.x) + bfhi(w2.x);
        a2 += bflo(w.y) + bflo(w2.y); a3 += bfhi(w.y) + bfhi(w2.y);
        a4 += bflo(w.z) + bflo(w2.z); a5 += bfhi(w.z) + bfhi(w2.z);
        a6 += bflo(w.w) + bflo(w2.w); a7 += bfhi(w.w) + bfhi(w2.w);
    }
    for (; j < end; j += 8) {
        int s = csr[j];
        uint4 w = *reinterpret_cast<const uint4*>(ht + (size_t)s * 64 + 8 * g);
        a0 += bflo(w.x); a1 += bfhi(w.x); a2 += bflo(w.y); a3 += bfhi(w.y);
        a4 += bflo(w.z); a5 += bfhi(w.z); a6 += bflo(w.w); a7 += bfhi(w.w);
    }

    #pragma unroll
    for (int off = 8; off < 64; off <<= 1) {
        a0 += __shfl_xor(a0, off); a1 += __shfl_xor(a1, off);
        a2 += __shfl_xor(a2, off); a3 += __shfl_xor(a3, off);
        a4 += __shfl_xor(a4, off); a5 += __shfl_xor(a5, off);
        a6 += __shfl_xor(a6, off); a7 += __shfl_xor(a7, off);
    }

    if (q == 0) {
        uint4 sw = *reinterpret_cast<const uint4*>(ht + (size_t)wid * 64 + 8 * g);
        a0 += bflo(sw.x); a1 += bfhi(sw.x); a2 += bflo(sw.y); a3 += bfhi(sw.y);
        a4 += bflo(sw.z); a5 += bfhi(sw.z); a6 += bflo(sw.w); a7 += bfhi(sw.w);
        float di = dinv[wid];
        const float4* bp = reinterpret_cast<const float4*>(b1 + 8 * g);
        float4 bA = bp[0], bB = bp[1];
        float4 vA, vB;
        vA.x = fmaxf(di * a0 + bA.x, 0.f); vA.y = fmaxf(di * a1 + bA.y, 0.f);
        vA.z = fmaxf(di * a2 + bA.z, 0.f); vA.w = fmaxf(di * a3 + bA.w, 0.f);
        vB.x = fmaxf(di * a4 + bB.x, 0.f); vB.y = fmaxf(di * a5 + bB.y, 0.f);
        vB.z = fmaxf(di * a6 + bB.z, 0.f); vB.w = fmaxf(di * a7 + bB.w, 0.f);
        float4* hp = reinterpret_cast<float4*>(h + (size_t)wid * 64 + 8 * g);
        hp[0] = vA; hp[1] = vB;
    }
}

// ---------------- layer 2 GEMM: htp = bf16((h@W2)[:, :32]*dinv), htm = f32 col 32 ----------------

__global__ __launch_bounds__(256, 1) void k_gemm2(const float* __restrict__ h,
                                                  const float* __restrict__ W2,
                                                  const float* __restrict__ dinv,
                                                  unsigned short* __restrict__ htp,
                                                  float* __restrict__ htm) {
    __shared__ float w[64 * 36];   // padded stride 36 for float4 alignment
    for (int t = threadIdx.x; t < 64 * 36; t += 256) {
        int k = t / 36, c = t - k * 36;
        w[t] = (c < D2) ? W2[k * D2 + c] : 0.f;
    }
    __syncthreads();

    int i = blockIdx.x * 256 + threadIdx.x;
    if (i >= NN) return;

    float acc[36];
    #pragma unroll
    for (int c = 0; c < 36; ++c) acc[c] = 0.f;

    const float4* xp = reinterpret_cast<const float4*>(h + (size_t)i * 64);
    #pragma unroll
    for (int kc = 0; kc < 4; ++kc) {
        float4 c0 = xp[4 * kc + 0], c1 = xp[4 * kc + 1];
        float4 c2 = xp[4 * kc + 2], c3 = xp[4 * kc + 3];
        float xs[16] = {c0.x, c0.y, c0.z, c0.w, c1.x, c1.y, c1.z, c1.w,
                        c2.x, c2.y, c2.z, c2.w, c3.x, c3.y, c3.z, c3.w};
        #pragma unroll
        for (int kk = 0; kk < 16; ++kk) {
            float xk = xs[kk];
            const float4* wr = reinterpret_cast<const float4*>(w + (16 * kc + kk) * 36);
            #pragma unroll
            for (int c4 = 0; c4 < 9; ++c4) {
                float4 wv = wr[c4];
                acc[4 * c4 + 0] += xk * wv.x;
                acc[4 * c4 + 1] += xk * wv.y;
                acc[4 * c4 + 2] += xk * wv.z;
                acc[4 * c4 + 3] += xk * wv.w;
            }
        }
    }

    float di = dinv[i];
    uint4* pp = reinterpret_cast<uint4*>(htp + (size_t)i * 32);
    #pragma unroll
    for (int q = 0; q < 4; ++q) {
        uint4 v;
        v.x = pack2(acc[8 * q + 0] * di, acc[8 * q + 1] * di);
        v.y = pack2(acc[8 * q + 2] * di, acc[8 * q + 3] * di);
        v.z = pack2(acc[8 * q + 4] * di, acc[8 * q + 5] * di);
        v.w = pack2(acc[8 * q + 6] * di, acc[8 * q + 7] * di);
        pp[q] = v;
    }
    htm[i] = acc[32] * di;
}

// ---------------- layer 2 gather (+ epilogue): 8 slots x 8 feat-groups (uint2) + mass ----------------

__global__ __launch_bounds__(256) void k_gather2(const unsigned short* __restrict__ htp,
                                                 const float* __restrict__ htm,
                                                 const int* __restrict__ rs,
                                                 const int* __restrict__ csr,
                                                 const float* __restrict__ dinv,
                                                 const float* __restrict__ b2,
                                                 float* __restrict__ out) {
    int wid = (blockIdx.x * 256 + threadIdx.x) >> 6;
    if (wid >= NN) return;
    int lane = threadIdx.x & 63;
    int q = lane >> 3;     // neighbor slot 0..7
    int g = lane & 7;      // feats 4g..4g+3
    int beg = rs[wid], end = rs[wid + 1];

    float a0 = 0.f, a1 = 0.f, a2 = 0.f, a3 = 0.f;
    int j = beg + q;
    for (; j + 8 < end; j += 16) {
        int s  = csr[j];
        int s2 = csr[j + 8];
        uint2 w  = *reinterpret_cast<const uint2*>(htp + (size_t)s  * 32 + 4 * g);
        uint2 w2 = *reinterpret_cast<const uint2*>(htp + (size_t)s2 * 32 + 4 * g);
        a0 += bflo(w.x) + bflo(w2.x); a1 += bfhi(w.x) + bfhi(w2.x);
        a2 += bflo(w.y) + bflo(w2.y); a3 += bfhi(w.y) + bfhi(w2.y);
    }
    for (; j < end; j += 8) {
        int s = csr[j];
        uint2 w = *reinterpret_cast<const uint2*>(htp + (size_t)s * 32 + 4 * g);
        a0 += bflo(w.x); a1 += bfhi(w.x); a2 += bflo(w.y); a3 += bfhi(w.y);
    }

    // mass column: per-lane strided, f32 table
    float m = 0.f;
    for (int jm = beg + lane; jm < end; jm += 64) m += htm[csr[jm]];

    #pragma unroll
    for (int off = 8; off < 64; off <<= 1) {
        a0 += __shfl_xor(a0, off); a1 += __shfl_xor(a1, off);
        a2 += __shfl_xor(a2, off); a3 += __shfl_xor(a3, off);
    }
    m += __shfl_xor(m, 1);  m += __shfl_xor(m, 2);  m += __shfl_xor(m, 4);
    m += __shfl_xor(m, 8);  m += __shfl_xor(m, 16); m += __shfl_xor(m, 32);

    float di = dinv[wid];
    if (q == 0) {
        uint2 sw = *reinterpret_cast<const uint2*>(htp + (size_t)wid * 32 + 4 * g);
        a0 += bflo(sw.x); a1 += bfhi(sw.x); a2 += bflo(sw.y); a3 += bfhi(sw.y);
        const float4* bp = reinterpret_cast<const float4*>(b2 + 4 * g);
        float4 bv = bp[0];
        float4 v;
        v.x = di * a0 + bv.x; v.y = di * a1 + bv.y;
        v.z = di * a2 + bv.z; v.w = di * a3 + bv.w;
        *reinterpret_cast<float4*>(out + (size_t)wid * 32 + 4 * g) = v;
    }
    if (lane == 0) {
        float v = di * (m + htm[wid]) + b2[32];
        out[(size_t)NN * 32 + wid] = expf(v);
    }
}

extern "C" void kernel_launch(void* const* d_in, const int* in_sizes, int n_in,
                              void* d_out, int out_size, void* d_ws, size_t ws_size,
                              hipStream_t stream) {
    const float* x  = (const float*)d_in[0];
    const float* W1 = (const float*)d_in[1];
    const float* b1 = (const float*)d_in[2];
    const float* W2 = (const float*)d_in[3];
    const float* b2 = (const float*)d_in[4];
    const int*   ei = (const int*)d_in[5];
    const int* src = ei;
    const int* dst = ei + NE;
    float* out = (float*)d_out;

    // workspace layout
    char* p = (char*)d_ws;
    int* gbcnt  = (int*)p;              p += sizeof(int) * NBUCK;
    int* bbase  = (int*)p;              p += sizeof(int) * (NBUCK + 1);
    int* gcur   = (int*)p;              p += sizeof(int) * NBUCK;
    p = (char*)(((uintptr_t)p + 255) & ~(uintptr_t)255);
    int* rs     = (int*)p;              p += sizeof(int) * (NN + 1);
    p = (char*)(((uintptr_t)p + 255) & ~(uintptr_t)255);
    int* csr    = (int*)p;              p += sizeof(int) * NE;
    p = (char*)(((uintptr_t)p + 255) & ~(uintptr_t)255);
    unsigned* pairs = (unsigned*)p;     p += sizeof(unsigned) * NE;
    p = (char*)(((uintptr_t)p + 255) & ~(uintptr_t)255);
    float* dinv = (float*)p;            p += sizeof(float) * NN;
    p = (char*)(((uintptr_t)p + 255) & ~(uintptr_t)255);
    unsigned short* ht1 = (unsigned short*)p; p += sizeof(unsigned short) * (size_t)NN * 64;
    p = (char*)(((uintptr_t)p + 255) & ~(uintptr_t)255);
    float* h    = (float*)p;            p += sizeof(float) * (size_t)NN * 64;
    p = (char*)(((uintptr_t)p + 255) & ~(uintptr_t)255);
    unsigned short* htp = (unsigned short*)p; p += sizeof(unsigned short) * (size_t)NN * 32;
    p = (char*)(((uintptr_t)p + 255) & ~(uintptr_t)255);
    float* htm  = (float*)p;            p += sizeof(float) * NN;

    // ---- CSR build (multisplit; also emits rs + dinv) ----
    hipMemsetAsync(gbcnt, 0, sizeof(int) * NBUCK, stream);
    k_hist<<<NTILE, 256, 0, stream>>>(dst, gbcnt);
    k_scanb<<<1, 256, 0, stream>>>(gbcnt, bbase, gcur, rs);
    k_split<<<NTILE, 256, 0, stream>>>(src, dst, gcur, pairs);
    k_bin2<<<NBUCK, 256, 0, stream>>>(pairs, bbase, csr, rs, dinv);

    // ---- layer 1 ----
    k_gemm1<<<(NN + 255) / 256, 256, 0, stream>>>(x, W1, dinv, ht1);
    k_gather1<<<(NN * 64 + 255) / 256, 256, 0, stream>>>(ht1, rs, csr, dinv, b1, h);

    // ---- layer 2 ----
    k_gemm2<<<(NN + 255) / 256, 256, 0, stream>>>(h, W2, dinv, htp, htm);
    k_gather2<<<(NN * 64 + 255) / 256, 256, 0, stream>>>(htp, htm, rs, csr, dinv, b2, out);
}